// Round 3
// baseline (423.188 us; speedup 1.0000x reference)
//
#include <hip/hip_runtime.h>
#include <hip/hip_bf16.h>

#define N_PTS 4096
#define M_PTS 16384
#define CIN   256
#define CSK   128
#define KDIM  384   // CIN + CSK
#define HDIM  256

typedef unsigned int  u32;
typedef unsigned short u16;

__device__ __forceinline__ float bf2f(u16 u) {
    union { u32 i; float f; } w; w.i = ((u32)u) << 16; return w.f;
}
__device__ __forceinline__ u16 f2bf(float f) {
    union { float f; u32 i; } w; w.f = f;
    u32 x = w.i;
    u32 r = x + 0x7fffu + ((x >> 16) & 1u);   // RTNE
    return (u16)(r >> 16);
}

// strict "better" with lower-index tie-break (jax top_k semantics)
__device__ __forceinline__ bool ltk(float s, int p, float t, int i) {
    return (s < t) || (s == t && p < i);
}

__device__ __forceinline__ void ins3(float s, int p,
                                     float& t0, float& t1, float& t2,
                                     int& i0, int& i1, int& i2) {
    if (ltk(s, p, t2, i2)) {
        if (ltk(s, p, t1, i1)) {
            t2 = t1; i2 = i1;
            if (ltk(s, p, t0, i0)) { t1 = t0; i1 = i0; t0 = s; i0 = p; }
            else                   { t1 = s;  i1 = p; }
        } else { t2 = s; i2 = p; }
    }
}

// ---------------------------------------------------------------------------
// Kernel 1: 3-NN + inverse-distance interpolation + concat -> A [M, 384] bf16
// Ranking replicates the reference's fp32 arithmetic BIT-EXACTLY:
//   d2 = (|q|^2 - 2*(q.p)) + |p|^2, all fp32,
//   |v|^2 = rnd(rnd(v0^2 + v1^2) + v2^2),
//   q.p  = fma(q2,p2, fma(q1,p1, rnd(q0*p0)))   (sgemm k-ascending fma chain)
// with lower-index tie-break on exact fp32 equality.
// ---------------------------------------------------------------------------
__global__ __launch_bounds__(256) void knn_build_A(
    const float* __restrict__ x,        // [N, 256]
    const float* __restrict__ pos,      // [N, 3]
    const float* __restrict__ x_skip,   // [M, 128]
    const float* __restrict__ pos_skip, // [M, 3]
    u16* __restrict__ A)                // [M, 384] bf16
{
    __shared__ float4 sp[N_PTS];        // 64 KB: (x, y, z, |p|^2 fp32-replicated)
    const int tid = threadIdx.x;
    for (int i = tid; i < N_PTS; i += 256) {
        float px = pos[3 * i], py = pos[3 * i + 1], pz = pos[3 * i + 2];
        float pn = __fadd_rn(__fadd_rn(__fmul_rn(px, px), __fmul_rn(py, py)),
                             __fmul_rn(pz, pz));
        sp[i] = make_float4(px, py, pz, pn);
    }
    __syncthreads();

    const int wave = tid >> 6;
    const int lane = tid & 63;
    const int qbase = blockIdx.x * 32;  // 512 blocks * 32 queries = 16384

    for (int qi = 0; qi < 8; ++qi) {
        const int m = qbase + qi * 4 + wave;
        const float qx = pos_skip[3 * m];
        const float qy = pos_skip[3 * m + 1];
        const float qz = pos_skip[3 * m + 2];
        const float qn = __fadd_rn(__fadd_rn(__fmul_rn(qx, qx), __fmul_rn(qy, qy)),
                                   __fmul_rn(qz, qz));

        float t0 = 3.4e38f, t1 = 3.4e38f, t2 = 3.4e38f;
        int   i0 = 0x7fffffff, i1 = 0x7fffffff, i2 = 0x7fffffff;

        #pragma unroll 4
        for (int p = lane; p < N_PTS; p += 64) {
            float4 v = sp[p];
            // b = q.p as an fma chain, k ascending (replicates sgemm/XLA dot)
            float b = __fmaf_rn(qz, v.z, __fmaf_rn(qy, v.y, __fmul_rn(qx, v.x)));
            // d2 = (qn - 2b) + pn   (2b exact; association as in the reference)
            float s = __fadd_rn(__fsub_rn(qn, __fmul_rn(2.0f, b)), v.w);
            ins3(s, p, t0, t1, t2, i0, i1, i2);
        }

        // butterfly merge of sorted top-3 lists -> all lanes identical
        #pragma unroll
        for (int off = 1; off < 64; off <<= 1) {
            float o0 = __shfl_xor(t0, off);
            float o1 = __shfl_xor(t1, off);
            float o2 = __shfl_xor(t2, off);
            int   j0 = __shfl_xor(i0, off);
            int   j1 = __shfl_xor(i1, off);
            int   j2 = __shfl_xor(i2, off);
            ins3(o0, j0, t0, t1, t2, i0, i1, i2);
            ins3(o1, j1, t0, t1, t2, i0, i1, i2);
            ins3(o2, j2, t0, t1, t2, i0, i1, i2);
        }

        // inverse-distance weights (reference clamps d^2 at 1e-16), fp32
        float w0 = __fdiv_rn(1.0f, fmaxf(t0, 1e-16f));
        float w1 = __fdiv_rn(1.0f, fmaxf(t1, 1e-16f));
        float w2 = __fdiv_rn(1.0f, fmaxf(t2, 1e-16f));
        float inv = __fdiv_rn(1.0f, __fadd_rn(__fadd_rn(w0, w1), w2));
        float f0 = w0 * inv, f1 = w1 * inv, f2 = w2 * inv;

        // blend features: lane handles 4 channels (float4), 64 lanes = 256 ch
        const float4* r0 = reinterpret_cast<const float4*>(x + (size_t)i0 * CIN);
        const float4* r1 = reinterpret_cast<const float4*>(x + (size_t)i1 * CIN);
        const float4* r2 = reinterpret_cast<const float4*>(x + (size_t)i2 * CIN);
        float4 a = r0[lane], b = r1[lane], c = r2[lane];
        ushort4 h;
        h.x = f2bf(f0 * a.x + f1 * b.x + f2 * c.x);
        h.y = f2bf(f0 * a.y + f1 * b.y + f2 * c.y);
        h.z = f2bf(f0 * a.z + f1 * b.z + f2 * c.z);
        h.w = f2bf(f0 * a.w + f1 * b.w + f2 * c.w);
        u16* Arow = A + (size_t)m * KDIM;
        reinterpret_cast<ushort4*>(Arow)[lane] = h;

        // skip-feature part: lanes 0..31 cover 128 channels
        if (lane < 32) {
            float4 sv = reinterpret_cast<const float4*>(x_skip + (size_t)m * CSK)[lane];
            ushort4 g;
            g.x = f2bf(sv.x); g.y = f2bf(sv.y); g.z = f2bf(sv.z); g.w = f2bf(sv.w);
            reinterpret_cast<ushort4*>(Arow + CIN)[lane] = g;
        }
    }
}

// ---------------------------------------------------------------------------
// Kernel 2: H = relu(A @ W1 + b1)   A [M,384] bf16, W1 [384,256] f32
// BM=128, BN=64, BK=16, 256 threads, 8x4 per thread. H (f32) -> d_out scratch.
// ---------------------------------------------------------------------------
__global__ __launch_bounds__(256) void gemm1_kernel(
    const u16* __restrict__ A, const float* __restrict__ W1,
    const float* __restrict__ b1, float* __restrict__ H)
{
    __shared__ float As[16][132];  // [kk][row], pad to 132
    __shared__ float Bs[16][68];   // [kk][col]
    const int tid = threadIdx.x;
    const int bm = blockIdx.x * 128;
    const int bn = blockIdx.y * 64;
    const int tx = tid & 15;       // col group: cols tx*4 .. tx*4+3
    const int ty = tid >> 4;       // row group: rows ty*8 .. ty*8+7

    float acc[8][4];
    #pragma unroll
    for (int j = 0; j < 8; ++j)
        #pragma unroll
        for (int i = 0; i < 4; ++i) acc[j][i] = 0.f;

    const int ar = tid >> 1;            // 0..127
    const int ak = (tid & 1) * 8;       // 0 or 8

    for (int k0 = 0; k0 < KDIM; k0 += 16) {
        // stage A tile (bf16 -> f32), transposed to [kk][row]
        uint4 av = *reinterpret_cast<const uint4*>(
            A + (size_t)(bm + ar) * KDIM + k0 + ak);
        u32 aw[4] = {av.x, av.y, av.z, av.w};
        #pragma unroll
        for (int q = 0; q < 4; ++q) {
            As[ak + 2 * q][ar]     = bf2f((u16)(aw[q] & 0xffffu));
            As[ak + 2 * q + 1][ar] = bf2f((u16)(aw[q] >> 16));
        }
        // stage B tile
        {
            const int br = tid >> 4;        // 0..15
            const int bc = (tid & 15) * 4;  // 0..60
            float4 bv = *reinterpret_cast<const float4*>(
                W1 + (size_t)(k0 + br) * HDIM + bn + bc);
            *reinterpret_cast<float4*>(&Bs[br][bc]) = bv;
        }
        __syncthreads();
        #pragma unroll
        for (int kk = 0; kk < 16; ++kk) {
            float4 a0 = *reinterpret_cast<const float4*>(&As[kk][ty * 8]);
            float4 a1 = *reinterpret_cast<const float4*>(&As[kk][ty * 8 + 4]);
            float4 bb = *reinterpret_cast<const float4*>(&Bs[kk][tx * 4]);
            float a[8] = {a0.x, a0.y, a0.z, a0.w, a1.x, a1.y, a1.z, a1.w};
            float b[4] = {bb.x, bb.y, bb.z, bb.w};
            #pragma unroll
            for (int j = 0; j < 8; ++j)
                #pragma unroll
                for (int i = 0; i < 4; ++i)
                    acc[j][i] = fmaf(a[j], b[i], acc[j][i]);
        }
        __syncthreads();
    }

    const float4 bias = *reinterpret_cast<const float4*>(b1 + bn + tx * 4);
    const float bias_a[4] = {bias.x, bias.y, bias.z, bias.w};
    #pragma unroll
    for (int j = 0; j < 8; ++j) {
        const int r = bm + ty * 8 + j;
        float4 o;
        float v0 = acc[j][0] + bias_a[0];
        float v1 = acc[j][1] + bias_a[1];
        float v2 = acc[j][2] + bias_a[2];
        float v3 = acc[j][3] + bias_a[3];
        o.x = v0 > 0.f ? v0 : 0.f;
        o.y = v1 > 0.f ? v1 : 0.f;
        o.z = v2 > 0.f ? v2 : 0.f;
        o.w = v3 > 0.f ? v3 : 0.f;
        *reinterpret_cast<float4*>(H + (size_t)r * HDIM + bn + tx * 4) = o;
    }
}

// ---------------------------------------------------------------------------
// Kernel 3: out = H @ W2 + b2   (in-place on d_out: BM=64, BN=256 full width,
// each block reads only its own rows before writing them)
// ---------------------------------------------------------------------------
__global__ __launch_bounds__(256) void gemm2_kernel(
    const float* __restrict__ Hin, const float* __restrict__ W2,
    const float* __restrict__ b2, float* __restrict__ out)
{
    __shared__ float Hs[16][68];    // [kk][row]
    __shared__ float Ws[16][260];   // [kk][col]
    const int tid = threadIdx.x;
    const int bm = blockIdx.x * 64;
    const int tx = tid & 31;        // cols tx*4..+3 and 128+tx*4..+3
    const int ty = tid >> 5;        // rows ty*8..+7

    float acc[8][8];
    #pragma unroll
    for (int j = 0; j < 8; ++j)
        #pragma unroll
        for (int i = 0; i < 8; ++i) acc[j][i] = 0.f;

    for (int k0 = 0; k0 < HDIM; k0 += 16) {
        // stage H tile 64x16 -> Hs[kk][row]
        {
            const int r = tid >> 2, kk = (tid & 3) * 4;
            float4 v = *reinterpret_cast<const float4*>(
                Hin + (size_t)(bm + r) * HDIM + k0 + kk);
            Hs[kk + 0][r] = v.x; Hs[kk + 1][r] = v.y;
            Hs[kk + 2][r] = v.z; Hs[kk + 3][r] = v.w;
        }
        // stage W2 tile 16x256
        #pragma unroll
        for (int i = 0; i < 4; ++i) {
            const int flat = tid * 4 + i * 1024;
            const int r = flat >> 8, c = flat & 255;
            float4 v = *reinterpret_cast<const float4*>(
                W2 + (size_t)(k0 + r) * HDIM + c);
            *reinterpret_cast<float4*>(&Ws[r][c]) = v;
        }
        __syncthreads();
        #pragma unroll
        for (int kk = 0; kk < 16; ++kk) {
            float4 a0 = *reinterpret_cast<const float4*>(&Hs[kk][ty * 8]);
            float4 a1 = *reinterpret_cast<const float4*>(&Hs[kk][ty * 8 + 4]);
            float4 b0 = *reinterpret_cast<const float4*>(&Ws[kk][tx * 4]);
            float4 b1v = *reinterpret_cast<const float4*>(&Ws[kk][128 + tx * 4]);
            float a[8] = {a0.x, a0.y, a0.z, a0.w, a1.x, a1.y, a1.z, a1.w};
            float b[8] = {b0.x, b0.y, b0.z, b0.w, b1v.x, b1v.y, b1v.z, b1v.w};
            #pragma unroll
            for (int j = 0; j < 8; ++j)
                #pragma unroll
                for (int i = 0; i < 8; ++i)
                    acc[j][i] = fmaf(a[j], b[i], acc[j][i]);
        }
        __syncthreads();
    }

    const float4 c0 = *reinterpret_cast<const float4*>(b2 + tx * 4);
    const float4 c1 = *reinterpret_cast<const float4*>(b2 + 128 + tx * 4);
    #pragma unroll
    for (int j = 0; j < 8; ++j) {
        const int r = bm + ty * 8 + j;
        float4 o0, o1;
        o0.x = acc[j][0] + c0.x; o0.y = acc[j][1] + c0.y;
        o0.z = acc[j][2] + c0.z; o0.w = acc[j][3] + c0.w;
        o1.x = acc[j][4] + c1.x; o1.y = acc[j][5] + c1.y;
        o1.z = acc[j][6] + c1.z; o1.w = acc[j][7] + c1.w;
        *reinterpret_cast<float4*>(out + (size_t)r * HDIM + tx * 4) = o0;
        *reinterpret_cast<float4*>(out + (size_t)r * HDIM + 128 + tx * 4) = o1;
    }
}

// ---------------------------------------------------------------------------
extern "C" void kernel_launch(void* const* d_in, const int* in_sizes, int n_in,
                              void* d_out, int out_size, void* d_ws, size_t ws_size,
                              hipStream_t stream) {
    const float* x        = (const float*)d_in[0];
    const float* pos      = (const float*)d_in[1];
    const float* x_skip   = (const float*)d_in[2];
    const float* pos_skip = (const float*)d_in[3];
    const float* W1       = (const float*)d_in[4];
    const float* b1       = (const float*)d_in[5];
    const float* W2       = (const float*)d_in[6];
    const float* b2       = (const float*)d_in[7];

    u16*   A   = (u16*)d_ws;        // [16384, 384] bf16 = 12.6 MB
    float* out = (float*)d_out;     // also used as H scratch between gemm1/gemm2

    knn_build_A<<<512, 256, 0, stream>>>(x, pos, x_skip, pos_skip, A);
    gemm1_kernel<<<dim3(128, 4), 256, 0, stream>>>(A, W1, b1, out);
    gemm2_kernel<<<dim3(256, 1), 256, 0, stream>>>(out, W2, b2, out);
}

// Round 4
// 187.290 us; speedup vs baseline: 2.2595x; 2.2595x over previous
//
#include <hip/hip_runtime.h>
#include <hip/hip_bf16.h>

#define N_PTS 4096
#define M_PTS 16384
#define CIN   256
#define CSK   128
#define KDIM  384   // CIN + CSK
#define HDIM  256
#define NSHARD 8
#define SHPTS (N_PTS / NSHARD)   // 512

typedef unsigned int  u32;
typedef unsigned short u16;

__device__ __forceinline__ float bf2f(u16 u) {
    union { u32 i; float f; } w; w.i = ((u32)u) << 16; return w.f;
}
__device__ __forceinline__ u16 f2bf(float f) {
    union { float f; u32 i; } w; w.f = f;
    u32 x = w.i;
    u32 r = x + 0x7fffu + ((x >> 16) & 1u);   // RTNE
    return (u16)(r >> 16);
}

// strict "better" with lower-index tie-break (stable-sort semantics)
__device__ __forceinline__ bool ltk(float s, int p, float t, int i) {
    return (s < t) || (s == t && p < i);
}

__device__ __forceinline__ void ins3(float s, int p,
                                     float& t0, float& t1, float& t2,
                                     int& i0, int& i1, int& i2) {
    if (ltk(s, p, t2, i2)) {
        if (ltk(s, p, t1, i1)) {
            t2 = t1; i2 = i1;
            if (ltk(s, p, t0, i0)) { t1 = t0; i1 = i0; t0 = s; i0 = p; }
            else                   { t1 = s;  i1 = p; }
        } else { t2 = s; i2 = p; }
    }
}

// ---------------------------------------------------------------------------
// Kernel 0: pack pos -> (x, y, z, |p|^2) with the reference's exact fp32 |p|^2
// ---------------------------------------------------------------------------
__global__ __launch_bounds__(256) void pack_pos4(
    const float* __restrict__ pos, float4* __restrict__ pos4)
{
    const int i = blockIdx.x * 256 + threadIdx.x;
    if (i < N_PTS) {
        float px = pos[3 * i], py = pos[3 * i + 1], pz = pos[3 * i + 2];
        float pn = __fadd_rn(__fadd_rn(__fmul_rn(px, px), __fmul_rn(py, py)),
                             __fmul_rn(pz, pz));
        pos4[i] = make_float4(px, py, pz, pn);
    }
}

// ---------------------------------------------------------------------------
// Kernel 1: sharded 3-NN scan. One query per THREAD, branchless top-3.
// grid (64 query-blocks, 8 shards). Bit-exact fp32 d^2:
//   d2 = (|q|^2 - 2*fma(qz,pz,fma(qy,py,qx*px))) + |p|^2
// Ascending index + strict < gives lower-index tie-break within a shard.
// cand[(m*3+k)*8 + shard] = (bits(d_k), idx_k)
// ---------------------------------------------------------------------------
__global__ __launch_bounds__(256) void knn_scan(
    const float4* __restrict__ pos4,
    const float* __restrict__ pos_skip,
    uint2* __restrict__ cand)
{
    const int m  = blockIdx.x * 256 + threadIdx.x;
    const int sh = blockIdx.y;
    const int pbase = sh * SHPTS;

    const float qx = pos_skip[3 * m];
    const float qy = pos_skip[3 * m + 1];
    const float qz = pos_skip[3 * m + 2];
    const float qn = __fadd_rn(__fadd_rn(__fmul_rn(qx, qx), __fmul_rn(qy, qy)),
                               __fmul_rn(qz, qz));

    float t0 = 3.4e38f, t1 = 3.4e38f, t2 = 3.4e38f;
    int   i0 = 0x7fffffff, i1 = 0x7fffffff, i2 = 0x7fffffff;

    #pragma unroll 8
    for (int j = 0; j < SHPTS; ++j) {
        float4 v = pos4[pbase + j];   // wave-uniform address -> scalar/L1 load
        float b = __fmaf_rn(qz, v.z, __fmaf_rn(qy, v.y, __fmul_rn(qx, v.x)));
        float s = __fadd_rn(__fsub_rn(qn, __fmul_rn(2.0f, b)), v.w);
        const int p = pbase + j;
        // branchless sorted top-3 insert (c0 => c1 => c2)
        float o0 = t0, o1 = t1, o2 = t2;
        int   a0 = i0, a1 = i1, a2 = i2;
        bool c0 = s < o0, c1 = s < o1, c2 = s < o2;
        t0 = c0 ? s : o0;               i0 = c0 ? p : a0;
        t1 = c0 ? o0 : (c1 ? s : o1);   i1 = c0 ? a0 : (c1 ? p : a1);
        t2 = c1 ? o1 : (c2 ? s : o2);   i2 = c1 ? a1 : (c2 ? p : a2);
    }

    uint2* c = cand + (size_t)m * 3 * NSHARD + sh;
    c[0]          = make_uint2(__float_as_uint(t0), (u32)i0);
    c[NSHARD]     = make_uint2(__float_as_uint(t1), (u32)i1);
    c[2 * NSHARD] = make_uint2(__float_as_uint(t2), (u32)i2);
}

// ---------------------------------------------------------------------------
// Kernel 2: merge 8 shards' top-3 + interpolate + concat -> A [M,384] bf16.
// One wave per query (blend code identical to the verified round-3 kernel).
// ---------------------------------------------------------------------------
__global__ __launch_bounds__(256) void knn_finish(
    const float* __restrict__ x,        // [N, 256]
    const float* __restrict__ x_skip,   // [M, 128]
    const uint2* __restrict__ cand,     // [M][3][8]
    u16* __restrict__ A)                // [M, 384] bf16
{
    const int tid  = threadIdx.x;
    const int wave = tid >> 6;
    const int lane = tid & 63;
    const int qbase = blockIdx.x * 32;  // 512 blocks * 32 queries

    for (int qi = 0; qi < 8; ++qi) {
        const int m = qbase + qi * 4 + wave;
        const uint2* c = cand + (size_t)m * 3 * NSHARD + (lane & 7);
        uint2 v0 = c[0], v1 = c[NSHARD], v2 = c[2 * NSHARD];
        float t0 = __uint_as_float(v0.x), t1 = __uint_as_float(v1.x), t2 = __uint_as_float(v2.x);
        int   i0 = (int)v0.y, i1 = (int)v1.y, i2 = (int)v2.y;

        // butterfly merge across the 8 shards (every lane ends identical)
        #pragma unroll
        for (int off = 1; off < 8; off <<= 1) {
            float o0 = __shfl_xor(t0, off);
            float o1 = __shfl_xor(t1, off);
            float o2 = __shfl_xor(t2, off);
            int   j0 = __shfl_xor(i0, off);
            int   j1 = __shfl_xor(i1, off);
            int   j2 = __shfl_xor(i2, off);
            ins3(o0, j0, t0, t1, t2, i0, i1, i2);
            ins3(o1, j1, t0, t1, t2, i0, i1, i2);
            ins3(o2, j2, t0, t1, t2, i0, i1, i2);
        }

        // inverse-distance weights (reference clamps d^2 at 1e-16), fp32
        float w0 = __fdiv_rn(1.0f, fmaxf(t0, 1e-16f));
        float w1 = __fdiv_rn(1.0f, fmaxf(t1, 1e-16f));
        float w2 = __fdiv_rn(1.0f, fmaxf(t2, 1e-16f));
        float inv = __fdiv_rn(1.0f, __fadd_rn(__fadd_rn(w0, w1), w2));
        float f0 = w0 * inv, f1 = w1 * inv, f2 = w2 * inv;

        // blend features: lane handles 4 channels (float4), 64 lanes = 256 ch
        const float4* r0 = reinterpret_cast<const float4*>(x + (size_t)i0 * CIN);
        const float4* r1 = reinterpret_cast<const float4*>(x + (size_t)i1 * CIN);
        const float4* r2 = reinterpret_cast<const float4*>(x + (size_t)i2 * CIN);
        float4 a = r0[lane], b = r1[lane], c4 = r2[lane];
        ushort4 h;
        h.x = f2bf(f0 * a.x + f1 * b.x + f2 * c4.x);
        h.y = f2bf(f0 * a.y + f1 * b.y + f2 * c4.y);
        h.z = f2bf(f0 * a.z + f1 * b.z + f2 * c4.z);
        h.w = f2bf(f0 * a.w + f1 * b.w + f2 * c4.w);
        u16* Arow = A + (size_t)m * KDIM;
        reinterpret_cast<ushort4*>(Arow)[lane] = h;

        // skip-feature part: lanes 0..31 cover 128 channels
        if (lane < 32) {
            float4 sv = reinterpret_cast<const float4*>(x_skip + (size_t)m * CSK)[lane];
            ushort4 g;
            g.x = f2bf(sv.x); g.y = f2bf(sv.y); g.z = f2bf(sv.z); g.w = f2bf(sv.w);
            reinterpret_cast<ushort4*>(Arow + CIN)[lane] = g;
        }
    }
}

// ---------------------------------------------------------------------------
// Kernel 3: H = relu(A @ W1 + b1)   A [M,384] bf16, W1 [384,256] f32
// ---------------------------------------------------------------------------
__global__ __launch_bounds__(256) void gemm1_kernel(
    const u16* __restrict__ A, const float* __restrict__ W1,
    const float* __restrict__ b1, float* __restrict__ H)
{
    __shared__ float As[16][132];
    __shared__ float Bs[16][68];
    const int tid = threadIdx.x;
    const int bm = blockIdx.x * 128;
    const int bn = blockIdx.y * 64;
    const int tx = tid & 15;
    const int ty = tid >> 4;

    float acc[8][4];
    #pragma unroll
    for (int j = 0; j < 8; ++j)
        #pragma unroll
        for (int i = 0; i < 4; ++i) acc[j][i] = 0.f;

    const int ar = tid >> 1;
    const int ak = (tid & 1) * 8;

    for (int k0 = 0; k0 < KDIM; k0 += 16) {
        uint4 av = *reinterpret_cast<const uint4*>(
            A + (size_t)(bm + ar) * KDIM + k0 + ak);
        u32 aw[4] = {av.x, av.y, av.z, av.w};
        #pragma unroll
        for (int q = 0; q < 4; ++q) {
            As[ak + 2 * q][ar]     = bf2f((u16)(aw[q] & 0xffffu));
            As[ak + 2 * q + 1][ar] = bf2f((u16)(aw[q] >> 16));
        }
        {
            const int br = tid >> 4;
            const int bc = (tid & 15) * 4;
            float4 bv = *reinterpret_cast<const float4*>(
                W1 + (size_t)(k0 + br) * HDIM + bn + bc);
            *reinterpret_cast<float4*>(&Bs[br][bc]) = bv;
        }
        __syncthreads();
        #pragma unroll
        for (int kk = 0; kk < 16; ++kk) {
            float4 a0 = *reinterpret_cast<const float4*>(&As[kk][ty * 8]);
            float4 a1 = *reinterpret_cast<const float4*>(&As[kk][ty * 8 + 4]);
            float4 bb = *reinterpret_cast<const float4*>(&Bs[kk][tx * 4]);
            float a[8] = {a0.x, a0.y, a0.z, a0.w, a1.x, a1.y, a1.z, a1.w};
            float b[4] = {bb.x, bb.y, bb.z, bb.w};
            #pragma unroll
            for (int j = 0; j < 8; ++j)
                #pragma unroll
                for (int i = 0; i < 4; ++i)
                    acc[j][i] = fmaf(a[j], b[i], acc[j][i]);
        }
        __syncthreads();
    }

    const float4 bias = *reinterpret_cast<const float4*>(b1 + bn + tx * 4);
    const float bias_a[4] = {bias.x, bias.y, bias.z, bias.w};
    #pragma unroll
    for (int j = 0; j < 8; ++j) {
        const int r = bm + ty * 8 + j;
        float4 o;
        float v0 = acc[j][0] + bias_a[0];
        float v1 = acc[j][1] + bias_a[1];
        float v2 = acc[j][2] + bias_a[2];
        float v3 = acc[j][3] + bias_a[3];
        o.x = v0 > 0.f ? v0 : 0.f;
        o.y = v1 > 0.f ? v1 : 0.f;
        o.z = v2 > 0.f ? v2 : 0.f;
        o.w = v3 > 0.f ? v3 : 0.f;
        *reinterpret_cast<float4*>(H + (size_t)r * HDIM + bn + tx * 4) = o;
    }
}

// ---------------------------------------------------------------------------
// Kernel 4: out = H @ W2 + b2   (in-place on d_out: BM=64, BN=256)
// ---------------------------------------------------------------------------
__global__ __launch_bounds__(256) void gemm2_kernel(
    const float* __restrict__ Hin, const float* __restrict__ W2,
    const float* __restrict__ b2, float* __restrict__ out)
{
    __shared__ float Hs[16][68];
    __shared__ float Ws[16][260];
    const int tid = threadIdx.x;
    const int bm = blockIdx.x * 64;
    const int tx = tid & 31;
    const int ty = tid >> 5;

    float acc[8][8];
    #pragma unroll
    for (int j = 0; j < 8; ++j)
        #pragma unroll
        for (int i = 0; i < 8; ++i) acc[j][i] = 0.f;

    for (int k0 = 0; k0 < HDIM; k0 += 16) {
        {
            const int r = tid >> 2, kk = (tid & 3) * 4;
            float4 v = *reinterpret_cast<const float4*>(
                Hin + (size_t)(bm + r) * HDIM + k0 + kk);
            Hs[kk + 0][r] = v.x; Hs[kk + 1][r] = v.y;
            Hs[kk + 2][r] = v.z; Hs[kk + 3][r] = v.w;
        }
        #pragma unroll
        for (int i = 0; i < 4; ++i) {
            const int flat = tid * 4 + i * 1024;
            const int r = flat >> 8, c = flat & 255;
            float4 v = *reinterpret_cast<const float4*>(
                W2 + (size_t)(k0 + r) * HDIM + c);
            *reinterpret_cast<float4*>(&Ws[r][c]) = v;
        }
        __syncthreads();
        #pragma unroll
        for (int kk = 0; kk < 16; ++kk) {
            float4 a0 = *reinterpret_cast<const float4*>(&Hs[kk][ty * 8]);
            float4 a1 = *reinterpret_cast<const float4*>(&Hs[kk][ty * 8 + 4]);
            float4 b0 = *reinterpret_cast<const float4*>(&Ws[kk][tx * 4]);
            float4 b1v = *reinterpret_cast<const float4*>(&Ws[kk][128 + tx * 4]);
            float a[8] = {a0.x, a0.y, a0.z, a0.w, a1.x, a1.y, a1.z, a1.w};
            float b[8] = {b0.x, b0.y, b0.z, b0.w, b1v.x, b1v.y, b1v.z, b1v.w};
            #pragma unroll
            for (int j = 0; j < 8; ++j)
                #pragma unroll
                for (int i = 0; i < 8; ++i)
                    acc[j][i] = fmaf(a[j], b[i], acc[j][i]);
        }
        __syncthreads();
    }

    const float4 c0 = *reinterpret_cast<const float4*>(b2 + tx * 4);
    const float4 c1 = *reinterpret_cast<const float4*>(b2 + 128 + tx * 4);
    #pragma unroll
    for (int j = 0; j < 8; ++j) {
        const int r = bm + ty * 8 + j;
        float4 o0, o1;
        o0.x = acc[j][0] + c0.x; o0.y = acc[j][1] + c0.y;
        o0.z = acc[j][2] + c0.z; o0.w = acc[j][3] + c0.w;
        o1.x = acc[j][4] + c1.x; o1.y = acc[j][5] + c1.y;
        o1.z = acc[j][6] + c1.z; o1.w = acc[j][7] + c1.w;
        *reinterpret_cast<float4*>(out + (size_t)r * HDIM + tx * 4) = o0;
        *reinterpret_cast<float4*>(out + (size_t)r * HDIM + 128 + tx * 4) = o1;
    }
}

// ---------------------------------------------------------------------------
extern "C" void kernel_launch(void* const* d_in, const int* in_sizes, int n_in,
                              void* d_out, int out_size, void* d_ws, size_t ws_size,
                              hipStream_t stream) {
    const float* x        = (const float*)d_in[0];
    const float* pos      = (const float*)d_in[1];
    const float* x_skip   = (const float*)d_in[2];
    const float* pos_skip = (const float*)d_in[3];
    const float* W1       = (const float*)d_in[4];
    const float* b1       = (const float*)d_in[5];
    const float* W2       = (const float*)d_in[6];
    const float* b2       = (const float*)d_in[7];

    u16*   A    = (u16*)d_ws;                               // [16384,384] bf16 = 12.58 MB
    float* out  = (float*)d_out;                            // final out; scratch before gemm1
    uint2* cand = (uint2*)d_out;                            // [M][3][8] = 3.1 MB (dead after knn_finish)
    float4* pos4 = (float4*)((char*)d_out + (8u << 20));    // 64 KB @ +8MB (dead after knn_scan)

    pack_pos4 <<<16, 256, 0, stream>>>(pos, pos4);
    knn_scan  <<<dim3(64, NSHARD), 256, 0, stream>>>(pos4, pos_skip, cand);
    knn_finish<<<512, 256, 0, stream>>>(x, x_skip, cand, A);
    gemm1_kernel<<<dim3(128, 4), 256, 0, stream>>>(A, W1, b1, out);   // overwrites cand/pos4 region (both dead)
    gemm2_kernel<<<dim3(256, 1), 256, 0, stream>>>(out, W2, b2, out);
}

// Round 5
// 142.966 us; speedup vs baseline: 2.9601x; 1.3100x over previous
//
#include <hip/hip_runtime.h>
#include <hip/hip_bf16.h>

#define N_PTS 4096
#define M_PTS 16384
#define CIN   256
#define CSK   128
#define KDIM  384   // CIN + CSK
#define HDIM  256
#define NSHARD 16
#define SHPTS (N_PTS / NSHARD)   // 256

typedef unsigned int  u32;
typedef unsigned short u16;
typedef __attribute__((ext_vector_type(8))) short bf16x8;
typedef __attribute__((ext_vector_type(4))) float f32x4;

__device__ __forceinline__ float bf2f(u16 u) {
    union { u32 i; float f; } w; w.i = ((u32)u) << 16; return w.f;
}
__device__ __forceinline__ u16 f2bf(float f) {
    union { float f; u32 i; } w; w.f = f;
    u32 x = w.i;
    u32 r = x + 0x7fffu + ((x >> 16) & 1u);   // RTNE
    return (u16)(r >> 16);
}

// strict "better" with lower-index tie-break (stable-sort semantics)
__device__ __forceinline__ bool ltk(float s, int p, float t, int i) {
    return (s < t) || (s == t && p < i);
}

__device__ __forceinline__ void ins3(float s, int p,
                                     float& t0, float& t1, float& t2,
                                     int& i0, int& i1, int& i2) {
    if (ltk(s, p, t2, i2)) {
        if (ltk(s, p, t1, i1)) {
            t2 = t1; i2 = i1;
            if (ltk(s, p, t0, i0)) { t1 = t0; i1 = i0; t0 = s; i0 = p; }
            else                   { t1 = s;  i1 = p; }
        } else { t2 = s; i2 = p; }
    }
}

// branchless sorted top-3 insert, strict < (ascending index => stable)
#define INS3BL(s, p, t0, t1, t2, i0, i1, i2)                              \
    {                                                                     \
        float _o0 = t0, _o1 = t1, _o2 = t2;                               \
        int _a0 = i0, _a1 = i1, _a2 = i2;                                 \
        bool _c0 = (s) < _o0, _c1 = (s) < _o1, _c2 = (s) < _o2;           \
        t0 = _c0 ? (s) : _o0;              i0 = _c0 ? (p) : _a0;          \
        t1 = _c0 ? _o0 : (_c1 ? (s) : _o1); i1 = _c0 ? _a0 : (_c1 ? (p) : _a1); \
        t2 = _c1 ? _o1 : (_c2 ? (s) : _o2); i2 = _c1 ? _a1 : (_c2 ? (p) : _a2); \
    }

// ---------------------------------------------------------------------------
// Kernel 0: pack pos -> (x, y, z, |p|^2) with the reference's exact fp32 |p|^2
// ---------------------------------------------------------------------------
__global__ __launch_bounds__(256) void pack_pos4(
    const float* __restrict__ pos, float4* __restrict__ pos4)
{
    const int i = blockIdx.x * 256 + threadIdx.x;
    if (i < N_PTS) {
        float px = pos[3 * i], py = pos[3 * i + 1], pz = pos[3 * i + 2];
        float pn = __fadd_rn(__fadd_rn(__fmul_rn(px, px), __fmul_rn(py, py)),
                             __fmul_rn(pz, pz));
        pos4[i] = make_float4(px, py, pz, pn);
    }
}

// ---------------------------------------------------------------------------
// Kernel 1: sharded 3-NN scan. One query per THREAD; dual even/odd top-3
// accumulators (2x ILP on the serial insert chain). Bit-exact fp32 d^2.
// cand[(m*3+k)*16 + shard] = (bits(d_k), idx_k)
// ---------------------------------------------------------------------------
__global__ __launch_bounds__(256) void knn_scan(
    const float4* __restrict__ pos4,
    const float* __restrict__ pos_skip,
    uint2* __restrict__ cand)
{
    const int m  = blockIdx.x * 256 + threadIdx.x;
    const int sh = blockIdx.y;
    const int pbase = sh * SHPTS;

    const float qx = pos_skip[3 * m];
    const float qy = pos_skip[3 * m + 1];
    const float qz = pos_skip[3 * m + 2];
    const float qn = __fadd_rn(__fadd_rn(__fmul_rn(qx, qx), __fmul_rn(qy, qy)),
                               __fmul_rn(qz, qz));

    float e0 = 3.4e38f, e1 = 3.4e38f, e2 = 3.4e38f;
    int   ei0 = 0x7fffffff, ei1 = 0x7fffffff, ei2 = 0x7fffffff;
    float f0 = 3.4e38f, f1 = 3.4e38f, f2 = 3.4e38f;
    int   fi0 = 0x7fffffff, fi1 = 0x7fffffff, fi2 = 0x7fffffff;

    #pragma unroll 4
    for (int j = 0; j < SHPTS; j += 2) {
        float4 va = pos4[pbase + j];
        float4 vb = pos4[pbase + j + 1];
        float ba = __fmaf_rn(qz, va.z, __fmaf_rn(qy, va.y, __fmul_rn(qx, va.x)));
        float sa = __fadd_rn(__fsub_rn(qn, __fmul_rn(2.0f, ba)), va.w);
        float bb = __fmaf_rn(qz, vb.z, __fmaf_rn(qy, vb.y, __fmul_rn(qx, vb.x)));
        float sb = __fadd_rn(__fsub_rn(qn, __fmul_rn(2.0f, bb)), vb.w);
        const int pa = pbase + j, pb = pbase + j + 1;
        INS3BL(sa, pa, e0, e1, e2, ei0, ei1, ei2);
        INS3BL(sb, pb, f0, f1, f2, fi0, fi1, fi2);
    }
    // merge odd list into even (value, then lower-index tie-break)
    ins3(f0, fi0, e0, e1, e2, ei0, ei1, ei2);
    ins3(f1, fi1, e0, e1, e2, ei0, ei1, ei2);
    ins3(f2, fi2, e0, e1, e2, ei0, ei1, ei2);

    uint2* c = cand + (size_t)m * 3 * NSHARD + sh;
    c[0]          = make_uint2(__float_as_uint(e0), (u32)ei0);
    c[NSHARD]     = make_uint2(__float_as_uint(e1), (u32)ei1);
    c[2 * NSHARD] = make_uint2(__float_as_uint(e2), (u32)ei2);
}

// ---------------------------------------------------------------------------
// Kernel 2: merge 16 shards' top-3 + interpolate + concat -> A [M,384] bf16.
// One wave per query.
// ---------------------------------------------------------------------------
__global__ __launch_bounds__(256) void knn_finish(
    const float* __restrict__ x,        // [N, 256]
    const float* __restrict__ x_skip,   // [M, 128]
    const uint2* __restrict__ cand,     // [M][3][16]
    u16* __restrict__ A)                // [M, 384] bf16
{
    const int tid  = threadIdx.x;
    const int wave = tid >> 6;
    const int lane = tid & 63;
    const int qbase = blockIdx.x * 32;  // 512 blocks * 32 queries

    for (int qi = 0; qi < 8; ++qi) {
        const int m = qbase + qi * 4 + wave;
        const uint2* c = cand + (size_t)m * 3 * NSHARD + (lane & 15);
        uint2 v0 = c[0], v1 = c[NSHARD], v2 = c[2 * NSHARD];
        float t0 = __uint_as_float(v0.x), t1 = __uint_as_float(v1.x), t2 = __uint_as_float(v2.x);
        int   i0 = (int)v0.y, i1 = (int)v1.y, i2 = (int)v2.y;

        // butterfly merge across the 16 shards (every lane ends identical)
        #pragma unroll
        for (int off = 1; off < 16; off <<= 1) {
            float o0 = __shfl_xor(t0, off);
            float o1 = __shfl_xor(t1, off);
            float o2 = __shfl_xor(t2, off);
            int   j0 = __shfl_xor(i0, off);
            int   j1 = __shfl_xor(i1, off);
            int   j2 = __shfl_xor(i2, off);
            ins3(o0, j0, t0, t1, t2, i0, i1, i2);
            ins3(o1, j1, t0, t1, t2, i0, i1, i2);
            ins3(o2, j2, t0, t1, t2, i0, i1, i2);
        }

        // inverse-distance weights (reference clamps d^2 at 1e-16), fp32
        float w0 = __fdiv_rn(1.0f, fmaxf(t0, 1e-16f));
        float w1 = __fdiv_rn(1.0f, fmaxf(t1, 1e-16f));
        float w2 = __fdiv_rn(1.0f, fmaxf(t2, 1e-16f));
        float inv = __fdiv_rn(1.0f, __fadd_rn(__fadd_rn(w0, w1), w2));
        float g0 = w0 * inv, g1 = w1 * inv, g2 = w2 * inv;

        // blend features: lane handles 4 channels (float4), 64 lanes = 256 ch
        const float4* r0 = reinterpret_cast<const float4*>(x + (size_t)i0 * CIN);
        const float4* r1 = reinterpret_cast<const float4*>(x + (size_t)i1 * CIN);
        const float4* r2 = reinterpret_cast<const float4*>(x + (size_t)i2 * CIN);
        float4 a = r0[lane], b = r1[lane], c4 = r2[lane];
        ushort4 h;
        h.x = f2bf(g0 * a.x + g1 * b.x + g2 * c4.x);
        h.y = f2bf(g0 * a.y + g1 * b.y + g2 * c4.y);
        h.z = f2bf(g0 * a.z + g1 * b.z + g2 * c4.z);
        h.w = f2bf(g0 * a.w + g1 * b.w + g2 * c4.w);
        u16* Arow = A + (size_t)m * KDIM;
        reinterpret_cast<ushort4*>(Arow)[lane] = h;

        // skip-feature part: lanes 0..31 cover 128 channels
        if (lane < 32) {
            float4 sv = reinterpret_cast<const float4*>(x_skip + (size_t)m * CSK)[lane];
            ushort4 g;
            g.x = f2bf(sv.x); g.y = f2bf(sv.y); g.z = f2bf(sv.z); g.w = f2bf(sv.w);
            reinterpret_cast<ushort4*>(Arow + CIN)[lane] = g;
        }
    }
}

// ---------------------------------------------------------------------------
// Kernel 3 (MFMA): H = relu(A @ W1 + b1). A [M,384] bf16, W1 [384,256] f32.
// Block 128x64, 4 waves; wave = 32 rows x 64 cols = 2x4 tiles of 16x16.
// A-frags direct from global; W1 f32->bf16 staged transposed in LDS (pad 40).
// ---------------------------------------------------------------------------
__global__ __launch_bounds__(256) void gemm1_mfma(
    const u16* __restrict__ A, const float* __restrict__ W1,
    const float* __restrict__ b1, float* __restrict__ H)
{
    __shared__ alignas(16) u16 Bs[64][40];   // [col][k], 5.1 KB
    const int tid = threadIdx.x;
    const int w = tid >> 6, l = tid & 63;
    const int bm = blockIdx.x * 128;
    const int bn = blockIdx.y * 64;
    const int lr = l & 15, lg = l >> 4;      // row/col-in-tile, k-group

    f32x4 acc[2][4];
    #pragma unroll
    for (int mt = 0; mt < 2; ++mt)
        #pragma unroll
        for (int nt = 0; nt < 4; ++nt)
            acc[mt][nt] = (f32x4){0.f, 0.f, 0.f, 0.f};

    const int sc = tid >> 2;          // staging col 0..63
    const int sk = (tid & 3) * 8;     // staging k 0,8,16,24

    for (int k0 = 0; k0 < KDIM; k0 += 32) {
        // stage B: W1[k0+sk+j][bn+sc] -> Bs[sc][sk+j] (bf16)
        #pragma unroll
        for (int j = 0; j < 8; ++j)
            Bs[sc][sk + j] = f2bf(W1[(size_t)(k0 + sk + j) * HDIM + bn + sc]);
        __syncthreads();

        bf16x8 af[2];
        #pragma unroll
        for (int mt = 0; mt < 2; ++mt) {
            const int row = bm + w * 32 + mt * 16 + lr;
            af[mt] = *reinterpret_cast<const bf16x8*>(
                A + (size_t)row * KDIM + k0 + lg * 8);
        }
        #pragma unroll
        for (int nt = 0; nt < 4; ++nt) {
            bf16x8 bf = *reinterpret_cast<const bf16x8*>(&Bs[nt * 16 + lr][lg * 8]);
            #pragma unroll
            for (int mt = 0; mt < 2; ++mt)
                acc[mt][nt] = __builtin_amdgcn_mfma_f32_16x16x32_bf16(
                    af[mt], bf, acc[mt][nt], 0, 0, 0);
        }
        __syncthreads();
    }

    // epilogue: D[row=(l>>4)*4+i][col=l&15] per tile
    #pragma unroll
    for (int nt = 0; nt < 4; ++nt) {
        const int col = bn + nt * 16 + lr;
        const float bias = b1[col];
        #pragma unroll
        for (int mt = 0; mt < 2; ++mt) {
            #pragma unroll
            for (int i = 0; i < 4; ++i) {
                const int row = bm + w * 32 + mt * 16 + lg * 4 + i;
                float v = acc[mt][nt][i] + bias;
                H[(size_t)row * HDIM + col] = v > 0.f ? v : 0.f;
            }
        }
    }
}

// ---------------------------------------------------------------------------
// Kernel 4 (MFMA): out = H @ W2 + b2, in-place on d_out.
// Block 64 rows x FULL 256 cols (in-place safe: epilogue-only writes to own
// rows). 4 waves; wave = 16 rows x 256 cols = 16 tiles. H f32->bf16 at frag
// load; W2 f32->bf16 staged transposed in LDS.
// ---------------------------------------------------------------------------
__global__ __launch_bounds__(256) void gemm2_mfma(
    const float* __restrict__ Hin, const float* __restrict__ W2,
    const float* __restrict__ b2, float* __restrict__ out)
{
    __shared__ alignas(16) u16 Bs[256][40];  // [col][k], 20 KB
    const int tid = threadIdx.x;
    const int w = tid >> 6, l = tid & 63;
    const int bm = blockIdx.x * 64;
    const int lr = l & 15, lg = l >> 4;

    f32x4 acc[16];
    #pragma unroll
    for (int nt = 0; nt < 16; ++nt) acc[nt] = (f32x4){0.f, 0.f, 0.f, 0.f};

    const int sc = tid >> 2;          // staging col base 0..63 (+cc*64)
    const int sk = (tid & 3) * 8;

    for (int k0 = 0; k0 < HDIM; k0 += 32) {
        #pragma unroll
        for (int cc = 0; cc < 4; ++cc) {
            const int c = cc * 64 + sc;
            #pragma unroll
            for (int j = 0; j < 8; ++j)
                Bs[c][sk + j] = f2bf(W2[(size_t)(k0 + sk + j) * HDIM + c]);
        }
        __syncthreads();

        // A frag: H row bm + w*16 + lr, k = k0 + lg*8 .. +8 (f32 -> bf16)
        const float* hp = Hin + (size_t)(bm + w * 16 + lr) * HDIM + k0 + lg * 8;
        float4 h0 = *reinterpret_cast<const float4*>(hp);
        float4 h1 = *reinterpret_cast<const float4*>(hp + 4);
        bf16x8 af;
        af[0] = (short)f2bf(h0.x); af[1] = (short)f2bf(h0.y);
        af[2] = (short)f2bf(h0.z); af[3] = (short)f2bf(h0.w);
        af[4] = (short)f2bf(h1.x); af[5] = (short)f2bf(h1.y);
        af[6] = (short)f2bf(h1.z); af[7] = (short)f2bf(h1.w);

        #pragma unroll
        for (int nt = 0; nt < 16; ++nt) {
            bf16x8 bf = *reinterpret_cast<const bf16x8*>(&Bs[nt * 16 + lr][lg * 8]);
            acc[nt] = __builtin_amdgcn_mfma_f32_16x16x32_bf16(af, bf, acc[nt], 0, 0, 0);
        }
        __syncthreads();
    }

    #pragma unroll
    for (int nt = 0; nt < 16; ++nt) {
        const int col = nt * 16 + lr;
        const float bias = b2[col];
        #pragma unroll
        for (int i = 0; i < 4; ++i) {
            const int row = bm + w * 16 + lg * 4 + i;
            out[(size_t)row * HDIM + col] = acc[nt][i] + bias;
        }
    }
}

// ---------------------------------------------------------------------------
extern "C" void kernel_launch(void* const* d_in, const int* in_sizes, int n_in,
                              void* d_out, int out_size, void* d_ws, size_t ws_size,
                              hipStream_t stream) {
    const float* x        = (const float*)d_in[0];
    const float* pos      = (const float*)d_in[1];
    const float* x_skip   = (const float*)d_in[2];
    const float* pos_skip = (const float*)d_in[3];
    const float* W1       = (const float*)d_in[4];
    const float* b1       = (const float*)d_in[5];
    const float* W2       = (const float*)d_in[6];
    const float* b2       = (const float*)d_in[7];

    u16*   A    = (u16*)d_ws;                               // [16384,384] bf16 = 12.58 MB
    float* out  = (float*)d_out;                            // final out; H scratch after knn
    uint2* cand = (uint2*)d_out;                            // [M][3][16] = 6.29 MB (dead after knn_finish)
    float4* pos4 = (float4*)((char*)d_out + (8u << 20));    // 64 KB @ +8MB (dead after knn_scan)

    pack_pos4 <<<16, 256, 0, stream>>>(pos, pos4);
    knn_scan  <<<dim3(64, NSHARD), 256, 0, stream>>>(pos4, pos_skip, cand);
    knn_finish<<<512, 256, 0, stream>>>(x, x_skip, cand, A);
    gemm1_mfma<<<dim3(128, 4), 256, 0, stream>>>(A, W1, b1, out);   // overwrites cand/pos4 (dead)
    gemm2_mfma<<<256, 256, 0, stream>>>(out, W2, b2, out);
}

// Round 6
// 140.368 us; speedup vs baseline: 3.0149x; 1.0185x over previous
//
#include <hip/hip_runtime.h>
#include <hip/hip_bf16.h>

#define N_PTS 4096
#define M_PTS 16384
#define CIN   256
#define CSK   128
#define KDIM  384   // CIN + CSK
#define HDIM  256
#define NSHARD 16
#define SHPTS (N_PTS / NSHARD)   // 256

typedef unsigned int  u32;
typedef unsigned short u16;
typedef __attribute__((ext_vector_type(8))) short bf16x8;
typedef __attribute__((ext_vector_type(4))) float f32x4;

__device__ __forceinline__ float bf2f(u16 u) {
    union { u32 i; float f; } w; w.i = ((u32)u) << 16; return w.f;
}
__device__ __forceinline__ u16 f2bf(float f) {
    union { float f; u32 i; } w; w.f = f;
    u32 x = w.i;
    u32 r = x + 0x7fffu + ((x >> 16) & 1u);   // RTNE
    return (u16)(r >> 16);
}

// strict "better" with lower-index tie-break (stable-sort semantics)
__device__ __forceinline__ bool ltk(float s, int p, float t, int i) {
    return (s < t) || (s == t && p < i);
}

__device__ __forceinline__ void ins3(float s, int p,
                                     float& t0, float& t1, float& t2,
                                     int& i0, int& i1, int& i2) {
    if (ltk(s, p, t2, i2)) {
        if (ltk(s, p, t1, i1)) {
            t2 = t1; i2 = i1;
            if (ltk(s, p, t0, i0)) { t1 = t0; i1 = i0; t0 = s; i0 = p; }
            else                   { t1 = s;  i1 = p; }
        } else { t2 = s; i2 = p; }
    }
}

// branchless sorted top-3 insert, strict < (ascending index => stable)
#define INS3BL(s, p, t0, t1, t2, i0, i1, i2)                              \
    {                                                                     \
        float _o0 = t0, _o1 = t1, _o2 = t2;                               \
        int _a0 = i0, _a1 = i1, _a2 = i2;                                 \
        bool _c0 = (s) < _o0, _c1 = (s) < _o1, _c2 = (s) < _o2;           \
        t0 = _c0 ? (s) : _o0;              i0 = _c0 ? (p) : _a0;          \
        t1 = _c0 ? _o0 : (_c1 ? (s) : _o1); i1 = _c0 ? _a0 : (_c1 ? (p) : _a1); \
        t2 = _c1 ? _o1 : (_c2 ? (s) : _o2); i2 = _c1 ? _a1 : (_c2 ? (p) : _a2); \
    }

// ---------------------------------------------------------------------------
// Kernel 0: pack pos -> (x, y, z, |p|^2) with the reference's exact fp32 |p|^2
// ---------------------------------------------------------------------------
__global__ __launch_bounds__(256) void pack_pos4(
    const float* __restrict__ pos, float4* __restrict__ pos4)
{
    const int i = blockIdx.x * 256 + threadIdx.x;
    if (i < N_PTS) {
        float px = pos[3 * i], py = pos[3 * i + 1], pz = pos[3 * i + 2];
        float pn = __fadd_rn(__fadd_rn(__fmul_rn(px, px), __fmul_rn(py, py)),
                             __fmul_rn(pz, pz));
        pos4[i] = make_float4(px, py, pz, pn);
    }
}

// ---------------------------------------------------------------------------
// Kernel 1: sharded 3-NN scan. One query per THREAD; FOUR interleaved top-3
// chains (4x ILP on the serial insert chain). Bit-exact fp32 d^2:
//   d2 = (|q|^2 - 2*fma(qz,pz,fma(qy,py,qx*px))) + |p|^2
// cand[(m*3+k)*16 + shard] = (bits(d_k), idx_k)
// ---------------------------------------------------------------------------
__global__ __launch_bounds__(256) void knn_scan(
    const float4* __restrict__ pos4,
    const float* __restrict__ pos_skip,
    uint2* __restrict__ cand)
{
    const int m  = blockIdx.x * 256 + threadIdx.x;
    const int sh = blockIdx.y;
    const int pbase = sh * SHPTS;

    const float qx = pos_skip[3 * m];
    const float qy = pos_skip[3 * m + 1];
    const float qz = pos_skip[3 * m + 2];
    const float qn = __fadd_rn(__fadd_rn(__fmul_rn(qx, qx), __fmul_rn(qy, qy)),
                               __fmul_rn(qz, qz));

    float e0[4], e1[4], e2[4];
    int   a0[4], a1[4], a2[4];
    #pragma unroll
    for (int c = 0; c < 4; ++c) {
        e0[c] = 3.4e38f; e1[c] = 3.4e38f; e2[c] = 3.4e38f;
        a0[c] = 0x7fffffff; a1[c] = 0x7fffffff; a2[c] = 0x7fffffff;
    }

    #pragma unroll 2
    for (int j = 0; j < SHPTS; j += 4) {
        #pragma unroll
        for (int c = 0; c < 4; ++c) {
            float4 v = pos4[pbase + j + c];
            float b = __fmaf_rn(qz, v.z, __fmaf_rn(qy, v.y, __fmul_rn(qx, v.x)));
            float s = __fadd_rn(__fsub_rn(qn, __fmul_rn(2.0f, b)), v.w);
            const int p = pbase + j + c;
            INS3BL(s, p, e0[c], e1[c], e2[c], a0[c], a1[c], a2[c]);
        }
    }
    // merge chains 1..3 into chain 0 (value, then lower-index tie-break)
    #pragma unroll
    for (int c = 1; c < 4; ++c) {
        ins3(e0[c], a0[c], e0[0], e1[0], e2[0], a0[0], a1[0], a2[0]);
        ins3(e1[c], a1[c], e0[0], e1[0], e2[0], a0[0], a1[0], a2[0]);
        ins3(e2[c], a2[c], e0[0], e1[0], e2[0], a0[0], a1[0], a2[0]);
    }

    uint2* c = cand + (size_t)m * 3 * NSHARD + sh;
    c[0]          = make_uint2(__float_as_uint(e0[0]), (u32)a0[0]);
    c[NSHARD]     = make_uint2(__float_as_uint(e1[0]), (u32)a1[0]);
    c[2 * NSHARD] = make_uint2(__float_as_uint(e2[0]), (u32)a2[0]);
}

// ---------------------------------------------------------------------------
// Kernel 2: merge 16 shards' top-3 + interpolate + concat -> A [M,384] bf16.
// ONE QUERY PER WAVE, one query-wave per grid slot (16384 waves total).
// ---------------------------------------------------------------------------
__global__ __launch_bounds__(256) void knn_finish(
    const float* __restrict__ x,        // [N, 256]
    const float* __restrict__ x_skip,   // [M, 128]
    const uint2* __restrict__ cand,     // [M][3][16]
    u16* __restrict__ A)                // [M, 384] bf16
{
    const int tid  = threadIdx.x;
    const int wave = tid >> 6;
    const int lane = tid & 63;
    const int m = blockIdx.x * 4 + wave;   // 4096 blocks * 4 waves = 16384

    const uint2* c = cand + (size_t)m * 3 * NSHARD + (lane & 15);
    uint2 v0 = c[0], v1 = c[NSHARD], v2 = c[2 * NSHARD];
    float t0 = __uint_as_float(v0.x), t1 = __uint_as_float(v1.x), t2 = __uint_as_float(v2.x);
    int   i0 = (int)v0.y, i1 = (int)v1.y, i2 = (int)v2.y;

    // butterfly merge across the 16 shards (every lane ends identical)
    #pragma unroll
    for (int off = 1; off < 16; off <<= 1) {
        float o0 = __shfl_xor(t0, off);
        float o1 = __shfl_xor(t1, off);
        float o2 = __shfl_xor(t2, off);
        int   j0 = __shfl_xor(i0, off);
        int   j1 = __shfl_xor(i1, off);
        int   j2 = __shfl_xor(i2, off);
        ins3(o0, j0, t0, t1, t2, i0, i1, i2);
        ins3(o1, j1, t0, t1, t2, i0, i1, i2);
        ins3(o2, j2, t0, t1, t2, i0, i1, i2);
    }

    // inverse-distance weights (reference clamps d^2 at 1e-16), fp32
    float w0 = __fdiv_rn(1.0f, fmaxf(t0, 1e-16f));
    float w1 = __fdiv_rn(1.0f, fmaxf(t1, 1e-16f));
    float w2 = __fdiv_rn(1.0f, fmaxf(t2, 1e-16f));
    float inv = __fdiv_rn(1.0f, __fadd_rn(__fadd_rn(w0, w1), w2));
    float g0 = w0 * inv, g1 = w1 * inv, g2 = w2 * inv;

    // blend features: lane handles 4 channels (float4), 64 lanes = 256 ch
    const float4* r0 = reinterpret_cast<const float4*>(x + (size_t)i0 * CIN);
    const float4* r1 = reinterpret_cast<const float4*>(x + (size_t)i1 * CIN);
    const float4* r2 = reinterpret_cast<const float4*>(x + (size_t)i2 * CIN);
    float4 a = r0[lane], b = r1[lane], c4 = r2[lane];
    ushort4 h;
    h.x = f2bf(g0 * a.x + g1 * b.x + g2 * c4.x);
    h.y = f2bf(g0 * a.y + g1 * b.y + g2 * c4.y);
    h.z = f2bf(g0 * a.z + g1 * b.z + g2 * c4.z);
    h.w = f2bf(g0 * a.w + g1 * b.w + g2 * c4.w);
    u16* Arow = A + (size_t)m * KDIM;
    reinterpret_cast<ushort4*>(Arow)[lane] = h;

    // skip-feature part: lanes 0..31 cover 128 channels
    if (lane < 32) {
        float4 sv = reinterpret_cast<const float4*>(x_skip + (size_t)m * CSK)[lane];
        ushort4 g;
        g.x = f2bf(sv.x); g.y = f2bf(sv.y); g.z = f2bf(sv.z); g.w = f2bf(sv.w);
        reinterpret_cast<ushort4*>(Arow + CIN)[lane] = g;
    }
}

// ---------------------------------------------------------------------------
// Kernel 3 (MFMA): H = relu(A @ W1 + b1). A [M,384] bf16, W1 [384,256] f32.
// Block 128x64, 4 waves; wave = 32 rows x 64 cols = 2x4 tiles of 16x16.
// ---------------------------------------------------------------------------
__global__ __launch_bounds__(256) void gemm1_mfma(
    const u16* __restrict__ A, const float* __restrict__ W1,
    const float* __restrict__ b1, float* __restrict__ H)
{
    __shared__ alignas(16) u16 Bs[64][40];   // [col][k], 5.1 KB
    const int tid = threadIdx.x;
    const int w = tid >> 6, l = tid & 63;
    const int bm = blockIdx.x * 128;
    const int bn = blockIdx.y * 64;
    const int lr = l & 15, lg = l >> 4;      // row/col-in-tile, k-group

    f32x4 acc[2][4];
    #pragma unroll
    for (int mt = 0; mt < 2; ++mt)
        #pragma unroll
        for (int nt = 0; nt < 4; ++nt)
            acc[mt][nt] = (f32x4){0.f, 0.f, 0.f, 0.f};

    const int sc = tid >> 2;          // staging col 0..63
    const int sk = (tid & 3) * 8;     // staging k 0,8,16,24

    for (int k0 = 0; k0 < KDIM; k0 += 32) {
        // stage B: W1[k0+sk+j][bn+sc] -> Bs[sc][sk+j] (bf16)
        #pragma unroll
        for (int j = 0; j < 8; ++j)
            Bs[sc][sk + j] = f2bf(W1[(size_t)(k0 + sk + j) * HDIM + bn + sc]);
        __syncthreads();

        bf16x8 af[2];
        #pragma unroll
        for (int mt = 0; mt < 2; ++mt) {
            const int row = bm + w * 32 + mt * 16 + lr;
            af[mt] = *reinterpret_cast<const bf16x8*>(
                A + (size_t)row * KDIM + k0 + lg * 8);
        }
        #pragma unroll
        for (int nt = 0; nt < 4; ++nt) {
            bf16x8 bf = *reinterpret_cast<const bf16x8*>(&Bs[nt * 16 + lr][lg * 8]);
            #pragma unroll
            for (int mt = 0; mt < 2; ++mt)
                acc[mt][nt] = __builtin_amdgcn_mfma_f32_16x16x32_bf16(
                    af[mt], bf, acc[mt][nt], 0, 0, 0);
        }
        __syncthreads();
    }

    // epilogue: D[row=(l>>4)*4+i][col=l&15] per tile
    #pragma unroll
    for (int nt = 0; nt < 4; ++nt) {
        const int col = bn + nt * 16 + lr;
        const float bias = b1[col];
        #pragma unroll
        for (int mt = 0; mt < 2; ++mt) {
            #pragma unroll
            for (int i = 0; i < 4; ++i) {
                const int row = bm + w * 32 + mt * 16 + lg * 4 + i;
                float v = acc[mt][nt][i] + bias;
                H[(size_t)row * HDIM + col] = v > 0.f ? v : 0.f;
            }
        }
    }
}

// ---------------------------------------------------------------------------
// Kernel 4 (MFMA): out = H @ W2 + b2, in-place on d_out.
// Block 64 rows x FULL 256 cols (in-place safe: each block reads only its own
// rows before writing them). 4 waves; wave = 16 rows x 256 cols = 16 tiles.
// ---------------------------------------------------------------------------
__global__ __launch_bounds__(256) void gemm2_mfma(
    const float* __restrict__ Hin, const float* __restrict__ W2,
    const float* __restrict__ b2, float* __restrict__ out)
{
    __shared__ alignas(16) u16 Bs[256][40];  // [col][k], 20 KB
    const int tid = threadIdx.x;
    const int w = tid >> 6, l = tid & 63;
    const int bm = blockIdx.x * 64;
    const int lr = l & 15, lg = l >> 4;

    f32x4 acc[16];
    #pragma unroll
    for (int nt = 0; nt < 16; ++nt) acc[nt] = (f32x4){0.f, 0.f, 0.f, 0.f};

    const int sc = tid >> 2;          // staging col base 0..63 (+cc*64)
    const int sk = (tid & 3) * 8;

    for (int k0 = 0; k0 < HDIM; k0 += 32) {
        #pragma unroll
        for (int cc = 0; cc < 4; ++cc) {
            const int c = cc * 64 + sc;
            #pragma unroll
            for (int j = 0; j < 8; ++j)
                Bs[c][sk + j] = f2bf(W2[(size_t)(k0 + sk + j) * HDIM + c]);
        }
        __syncthreads();

        // A frag: H row bm + w*16 + lr, k = k0 + lg*8 .. +8 (f32 -> bf16)
        const float* hp = Hin + (size_t)(bm + w * 16 + lr) * HDIM + k0 + lg * 8;
        float4 h0 = *reinterpret_cast<const float4*>(hp);
        float4 h1 = *reinterpret_cast<const float4*>(hp + 4);
        bf16x8 af;
        af[0] = (short)f2bf(h0.x); af[1] = (short)f2bf(h0.y);
        af[2] = (short)f2bf(h0.z); af[3] = (short)f2bf(h0.w);
        af[4] = (short)f2bf(h1.x); af[5] = (short)f2bf(h1.y);
        af[6] = (short)f2bf(h1.z); af[7] = (short)f2bf(h1.w);

        #pragma unroll
        for (int nt = 0; nt < 16; ++nt) {
            bf16x8 bf = *reinterpret_cast<const bf16x8*>(&Bs[nt * 16 + lr][lg * 8]);
            acc[nt] = __builtin_amdgcn_mfma_f32_16x16x32_bf16(af, bf, acc[nt], 0, 0, 0);
        }
        __syncthreads();
    }

    #pragma unroll
    for (int nt = 0; nt < 16; ++nt) {
        const int col = nt * 16 + lr;
        const float bias = b2[col];
        #pragma unroll
        for (int i = 0; i < 4; ++i) {
            const int row = bm + w * 16 + lg * 4 + i;
            out[(size_t)row * HDIM + col] = acc[nt][i] + bias;
        }
    }
}

// ---------------------------------------------------------------------------
extern "C" void kernel_launch(void* const* d_in, const int* in_sizes, int n_in,
                              void* d_out, int out_size, void* d_ws, size_t ws_size,
                              hipStream_t stream) {
    const float* x        = (const float*)d_in[0];
    const float* pos      = (const float*)d_in[1];
    const float* x_skip   = (const float*)d_in[2];
    const float* pos_skip = (const float*)d_in[3];
    const float* W1       = (const float*)d_in[4];
    const float* b1       = (const float*)d_in[5];
    const float* W2       = (const float*)d_in[6];
    const float* b2       = (const float*)d_in[7];

    u16*   A    = (u16*)d_ws;                               // [16384,384] bf16 = 12.58 MB
    float* out  = (float*)d_out;                            // final out; H scratch after knn
    uint2* cand = (uint2*)d_out;                            // [M][3][16] = 6.29 MB (dead after knn_finish)
    float4* pos4 = (float4*)((char*)d_out + (8u << 20));    // 64 KB @ +8MB (dead after knn_scan)

    pack_pos4 <<<16, 256, 0, stream>>>(pos, pos4);
    knn_scan  <<<dim3(64, NSHARD), 256, 0, stream>>>(pos4, pos_skip, cand);
    knn_finish<<<4096, 256, 0, stream>>>(x, x_skip, cand, A);
    gemm1_mfma<<<dim3(128, 4), 256, 0, stream>>>(A, W1, b1, out);   // overwrites cand/pos4 (dead)
    gemm2_mfma<<<256, 256, 0, stream>>>(out, W2, b2, out);
}

// Round 7
// 94.982 us; speedup vs baseline: 4.4554x; 1.4778x over previous
//
#include <hip/hip_runtime.h>
#include <hip/hip_bf16.h>

#define N_PTS 4096
#define M_PTS 16384
#define CIN   256
#define CSK   128
#define HDIM  256
#define NSHARD 16
#define SHPTS (N_PTS / NSHARD)   // 256

typedef unsigned int  u32;
typedef unsigned short u16;
typedef __attribute__((ext_vector_type(8))) short bf16x8;
typedef __attribute__((ext_vector_type(4))) float f32x4;

__device__ __forceinline__ u16 f2bf(float f) {
    union { float f; u32 i; } w; w.f = f;
    u32 x = w.i;
    u32 r = x + 0x7fffu + ((x >> 16) & 1u);   // RTNE
    return (u16)(r >> 16);
}

// strict "better" with lower-index tie-break (stable-sort semantics)
__device__ __forceinline__ bool ltk(float s, int p, float t, int i) {
    return (s < t) || (s == t && p < i);
}
__device__ __forceinline__ void ins3(float s, int p,
                                     float& t0, float& t1, float& t2,
                                     int& i0, int& i1, int& i2) {
    if (ltk(s, p, t2, i2)) {
        if (ltk(s, p, t1, i1)) {
            t2 = t1; i2 = i1;
            if (ltk(s, p, t0, i0)) { t1 = t0; i1 = i0; t0 = s; i0 = p; }
            else                   { t1 = s;  i1 = p; }
        } else { t2 = s; i2 = p; }
    }
}

// branchless sorted top-3 insert, strict < (ascending-index stream => stable)
#define INS3BL(s, p, t0, t1, t2, i0, i1, i2)                              \
    {                                                                     \
        float _o0 = t0, _o1 = t1, _o2 = t2;                               \
        int _a0 = i0, _a1 = i1, _a2 = i2;                                 \
        bool _c0 = (s) < _o0, _c1 = (s) < _o1, _c2 = (s) < _o2;           \
        t0 = _c0 ? (s) : _o0;              i0 = _c0 ? (p) : _a0;          \
        t1 = _c0 ? _o0 : (_c1 ? (s) : _o1); i1 = _c0 ? _a0 : (_c1 ? (p) : _a1); \
        t2 = _c1 ? _o1 : (_c2 ? (s) : _o2); i2 = _c1 ? _a1 : (_c2 ? (p) : _a2); \
    }

// ---------------------------------------------------------------------------
// Kernel 0: pack pos -> (x, y, z, |p|^2) with the reference's exact fp32 |p|^2
// ---------------------------------------------------------------------------
__global__ __launch_bounds__(256) void pack_pos4(
    const float* __restrict__ pos, float4* __restrict__ pos4)
{
    const int i = blockIdx.x * 256 + threadIdx.x;
    if (i < N_PTS) {
        float px = pos[3 * i], py = pos[3 * i + 1], pz = pos[3 * i + 2];
        float pn = __fadd_rn(__fadd_rn(__fmul_rn(px, px), __fmul_rn(py, py)),
                             __fmul_rn(pz, pz));
        pos4[i] = make_float4(px, py, pz, pn);
    }
}

// ---------------------------------------------------------------------------
// Kernel 1: sharded 3-NN scan, one query/thread, 4 interleaved top-3 chains,
// 8-point prefetch buffer (breaks the serial scalar-load->waitcnt chain).
// Bit-exact fp32 d^2 = (|q|^2 - 2*fma(qz,pz,fma(qy,py,qx*px))) + |p|^2.
// Output TRANSPOSED: candT[(sh*3+k)*M + m]  (coalesced write AND read).
// ---------------------------------------------------------------------------
__global__ __launch_bounds__(256) void knn_scan(
    const float4* __restrict__ pos4,
    const float* __restrict__ pos_skip,
    uint2* __restrict__ candT)
{
    const int m  = blockIdx.x * 256 + threadIdx.x;
    const int sh = blockIdx.y;
    const int pbase = sh * SHPTS;

    const float qx = pos_skip[3 * m];
    const float qy = pos_skip[3 * m + 1];
    const float qz = pos_skip[3 * m + 2];
    const float qn = __fadd_rn(__fadd_rn(__fmul_rn(qx, qx), __fmul_rn(qy, qy)),
                               __fmul_rn(qz, qz));

    float e0[4], e1[4], e2[4];
    int   a0[4], a1[4], a2[4];
    #pragma unroll
    for (int c = 0; c < 4; ++c) {
        e0[c] = 3.4e38f; e1[c] = 3.4e38f; e2[c] = 3.4e38f;
        a0[c] = 0x7fffffff; a1[c] = 0x7fffffff; a2[c] = 0x7fffffff;
    }

    float4 buf[8];
    #pragma unroll
    for (int t = 0; t < 8; ++t) buf[t] = pos4[pbase + t];

    for (int j0 = 0; j0 < SHPTS; j0 += 8) {
        float4 nxt[8];
        // unguarded prefetch: worst case reads 128B past pos4 (inside d_out) - safe
        #pragma unroll
        for (int t = 0; t < 8; ++t) nxt[t] = pos4[pbase + j0 + 8 + t];
        #pragma unroll
        for (int t = 0; t < 8; ++t) {
            float4 v = buf[t];
            float b = __fmaf_rn(qz, v.z, __fmaf_rn(qy, v.y, __fmul_rn(qx, v.x)));
            float s = __fadd_rn(__fsub_rn(qn, __fmul_rn(2.0f, b)), v.w);
            const int p = pbase + j0 + t;
            const int c = t & 3;
            INS3BL(s, p, e0[c], e1[c], e2[c], a0[c], a1[c], a2[c]);
        }
        #pragma unroll
        for (int t = 0; t < 8; ++t) buf[t] = nxt[t];
    }
    // merge chains 1..3 into chain 0 (value, then lower-index tie-break)
    #pragma unroll
    for (int c = 1; c < 4; ++c) {
        ins3(e0[c], a0[c], e0[0], e1[0], e2[0], a0[0], a1[0], a2[0]);
        ins3(e1[c], a1[c], e0[0], e1[0], e2[0], a0[0], a1[0], a2[0]);
        ins3(e2[c], a2[c], e0[0], e1[0], e2[0], a0[0], a1[0], a2[0]);
    }

    candT[(size_t)(sh * 3 + 0) * M_PTS + m] = make_uint2(__float_as_uint(e0[0]), (u32)a0[0]);
    candT[(size_t)(sh * 3 + 1) * M_PTS + m] = make_uint2(__float_as_uint(e1[0]), (u32)a1[0]);
    candT[(size_t)(sh * 3 + 2) * M_PTS + m] = make_uint2(__float_as_uint(e2[0]), (u32)a2[0]);
}

// ---------------------------------------------------------------------------
// Kernel 2: per-lane merge of 16 shard top-3 lists -> normalized weights+idx.
// Shard-ascending + k-ascending insert order with strict < == stable order.
// ---------------------------------------------------------------------------
__global__ __launch_bounds__(256) void knn_merge(
    const uint2* __restrict__ candT,   // [16][3][M]
    float4* __restrict__ nbrw,         // [M] (w0,w1,w2,-) normalized
    uint4* __restrict__ nbri)          // [M] (i0,i1,i2,-)
{
    const int m = blockIdx.x * 256 + threadIdx.x;

    float t0 = 3.4e38f, t1 = 3.4e38f, t2 = 3.4e38f;
    int   i0 = 0x7fffffff, i1 = 0x7fffffff, i2 = 0x7fffffff;

    #pragma unroll
    for (int sh = 0; sh < NSHARD; ++sh) {
        #pragma unroll
        for (int k = 0; k < 3; ++k) {
            uint2 v = candT[(size_t)(sh * 3 + k) * M_PTS + m];
            float s = __uint_as_float(v.x);
            const int p = (int)v.y;
            INS3BL(s, p, t0, t1, t2, i0, i1, i2);
        }
    }

    float w0 = __fdiv_rn(1.0f, fmaxf(t0, 1e-16f));
    float w1 = __fdiv_rn(1.0f, fmaxf(t1, 1e-16f));
    float w2 = __fdiv_rn(1.0f, fmaxf(t2, 1e-16f));
    float inv = __fdiv_rn(1.0f, __fadd_rn(__fadd_rn(w0, w1), w2));
    nbrw[m] = make_float4(w0 * inv, w1 * inv, w2 * inv, 0.f);
    nbri[m] = make_uint4((u32)i0, (u32)i1, (u32)i2, 0u);
}

// ---------------------------------------------------------------------------
// Kernel 3 (MFMA): Z = bf16(x) @ bf16(W1a)   [4096, 256], K=256, no bias.
// Block 128x64, 4 waves; wave = 32 rows x 64 cols = 2x4 tiles of 16x16.
// ---------------------------------------------------------------------------
__global__ __launch_bounds__(256) void gemm_Z(
    const float* __restrict__ x, const float* __restrict__ W1,
    float* __restrict__ Z)
{
    __shared__ alignas(16) u16 Bs[64][40];
    const int tid = threadIdx.x;
    const int w = tid >> 6, l = tid & 63;
    const int bm = blockIdx.x * 128;
    const int bn = blockIdx.y * 64;
    const int lr = l & 15, lg = l >> 4;

    f32x4 acc[2][4];
    #pragma unroll
    for (int mt = 0; mt < 2; ++mt)
        #pragma unroll
        for (int nt = 0; nt < 4; ++nt)
            acc[mt][nt] = (f32x4){0.f, 0.f, 0.f, 0.f};

    const int sc = tid >> 2;
    const int sk = (tid & 3) * 8;

    for (int k0 = 0; k0 < CIN; k0 += 32) {
        #pragma unroll
        for (int j = 0; j < 8; ++j)
            Bs[sc][sk + j] = f2bf(W1[(size_t)(k0 + sk + j) * HDIM + bn + sc]);
        __syncthreads();

        bf16x8 af[2];
        #pragma unroll
        for (int mt = 0; mt < 2; ++mt) {
            const float* xp = x + (size_t)(bm + w * 32 + mt * 16 + lr) * CIN + k0 + lg * 8;
            float4 h0 = *reinterpret_cast<const float4*>(xp);
            float4 h1 = *reinterpret_cast<const float4*>(xp + 4);
            af[mt][0] = (short)f2bf(h0.x); af[mt][1] = (short)f2bf(h0.y);
            af[mt][2] = (short)f2bf(h0.z); af[mt][3] = (short)f2bf(h0.w);
            af[mt][4] = (short)f2bf(h1.x); af[mt][5] = (short)f2bf(h1.y);
            af[mt][6] = (short)f2bf(h1.z); af[mt][7] = (short)f2bf(h1.w);
        }
        #pragma unroll
        for (int nt = 0; nt < 4; ++nt) {
            bf16x8 bf = *reinterpret_cast<const bf16x8*>(&Bs[nt * 16 + lr][lg * 8]);
            #pragma unroll
            for (int mt = 0; mt < 2; ++mt)
                acc[mt][nt] = __builtin_amdgcn_mfma_f32_16x16x32_bf16(
                    af[mt], bf, acc[mt][nt], 0, 0, 0);
        }
        __syncthreads();
    }

    #pragma unroll
    for (int nt = 0; nt < 4; ++nt) {
        const int col = bn + nt * 16 + lr;
        #pragma unroll
        for (int mt = 0; mt < 2; ++mt)
            #pragma unroll
            for (int i = 0; i < 4; ++i) {
                const int row = bm + w * 32 + mt * 16 + lg * 4 + i;
                Z[(size_t)row * HDIM + col] = acc[mt][nt][i];
            }
    }
}

// ---------------------------------------------------------------------------
// Kernel 4 (MFMA): S = bf16(x_skip) @ bf16(W1b), K=128; epilogue fuses the
// knn interpolation via Z-row gather: H = relu(S + sum_k w_k Z[i_k] + b1),
// H stored bf16. Block 128x64, 4 waves.
// ---------------------------------------------------------------------------
__global__ __launch_bounds__(256) void gemm_SH(
    const float* __restrict__ x_skip, const float* __restrict__ W1,
    const float* __restrict__ b1, const float* __restrict__ Z,
    const float4* __restrict__ nbrw, const uint4* __restrict__ nbri,
    u16* __restrict__ H)
{
    __shared__ alignas(16) u16 Bs[64][40];
    const int tid = threadIdx.x;
    const int w = tid >> 6, l = tid & 63;
    const int bm = blockIdx.x * 128;
    const int bn = blockIdx.y * 64;
    const int lr = l & 15, lg = l >> 4;

    f32x4 acc[2][4];
    #pragma unroll
    for (int mt = 0; mt < 2; ++mt)
        #pragma unroll
        for (int nt = 0; nt < 4; ++nt)
            acc[mt][nt] = (f32x4){0.f, 0.f, 0.f, 0.f};

    const int sc = tid >> 2;
    const int sk = (tid & 3) * 8;

    for (int k0 = 0; k0 < CSK; k0 += 32) {
        #pragma unroll
        for (int j = 0; j < 8; ++j)
            Bs[sc][sk + j] = f2bf(W1[(size_t)(CIN + k0 + sk + j) * HDIM + bn + sc]);
        __syncthreads();

        bf16x8 af[2];
        #pragma unroll
        for (int mt = 0; mt < 2; ++mt) {
            const float* xp = x_skip + (size_t)(bm + w * 32 + mt * 16 + lr) * CSK + k0 + lg * 8;
            float4 h0 = *reinterpret_cast<const float4*>(xp);
            float4 h1 = *reinterpret_cast<const float4*>(xp + 4);
            af[mt][0] = (short)f2bf(h0.x); af[mt][1] = (short)f2bf(h0.y);
            af[mt][2] = (short)f2bf(h0.z); af[mt][3] = (short)f2bf(h0.w);
            af[mt][4] = (short)f2bf(h1.x); af[mt][5] = (short)f2bf(h1.y);
            af[mt][6] = (short)f2bf(h1.z); af[mt][7] = (short)f2bf(h1.w);
        }
        #pragma unroll
        for (int nt = 0; nt < 4; ++nt) {
            bf16x8 bf = *reinterpret_cast<const bf16x8*>(&Bs[nt * 16 + lr][lg * 8]);
            #pragma unroll
            for (int mt = 0; mt < 2; ++mt)
                acc[mt][nt] = __builtin_amdgcn_mfma_f32_16x16x32_bf16(
                    af[mt], bf, acc[mt][nt], 0, 0, 0);
        }
        __syncthreads();
    }

    // epilogue: blend interpolated Z rows + bias + relu -> H (bf16)
    #pragma unroll
    for (int mt = 0; mt < 2; ++mt) {
        #pragma unroll
        for (int i = 0; i < 4; ++i) {
            const int row = bm + w * 32 + mt * 16 + lg * 4 + i;
            const float4 wv = nbrw[row];
            const uint4  iv = nbri[row];
            const float* z0 = Z + (size_t)iv.x * HDIM;
            const float* z1 = Z + (size_t)iv.y * HDIM;
            const float* z2 = Z + (size_t)iv.z * HDIM;
            #pragma unroll
            for (int nt = 0; nt < 4; ++nt) {
                const int col = bn + nt * 16 + lr;
                float zb = wv.x * z0[col] + wv.y * z1[col] + wv.z * z2[col];
                float v = acc[mt][nt][i] + zb + b1[col];
                H[(size_t)row * HDIM + col] = f2bf(v > 0.f ? v : 0.f);
            }
        }
    }
}

// ---------------------------------------------------------------------------
// Kernel 5 (MFMA): out = H @ W2 + b2.  H bf16 [16384,256], out f32.
// Block 128x64, 4 waves.
// ---------------------------------------------------------------------------
__global__ __launch_bounds__(256) void gemm2_mfma(
    const u16* __restrict__ H, const float* __restrict__ W2,
    const float* __restrict__ b2, float* __restrict__ out)
{
    __shared__ alignas(16) u16 Bs[64][40];
    const int tid = threadIdx.x;
    const int w = tid >> 6, l = tid & 63;
    const int bm = blockIdx.x * 128;
    const int bn = blockIdx.y * 64;
    const int lr = l & 15, lg = l >> 4;

    f32x4 acc[2][4];
    #pragma unroll
    for (int mt = 0; mt < 2; ++mt)
        #pragma unroll
        for (int nt = 0; nt < 4; ++nt)
            acc[mt][nt] = (f32x4){0.f, 0.f, 0.f, 0.f};

    const int sc = tid >> 2;
    const int sk = (tid & 3) * 8;

    for (int k0 = 0; k0 < HDIM; k0 += 32) {
        #pragma unroll
        for (int j = 0; j < 8; ++j)
            Bs[sc][sk + j] = f2bf(W2[(size_t)(k0 + sk + j) * HDIM + bn + sc]);
        __syncthreads();

        bf16x8 af[2];
        #pragma unroll
        for (int mt = 0; mt < 2; ++mt) {
            const int row = bm + w * 32 + mt * 16 + lr;
            af[mt] = *reinterpret_cast<const bf16x8*>(H + (size_t)row * HDIM + k0 + lg * 8);
        }
        #pragma unroll
        for (int nt = 0; nt < 4; ++nt) {
            bf16x8 bf = *reinterpret_cast<const bf16x8*>(&Bs[nt * 16 + lr][lg * 8]);
            #pragma unroll
            for (int mt = 0; mt < 2; ++mt)
                acc[mt][nt] = __builtin_amdgcn_mfma_f32_16x16x32_bf16(
                    af[mt], bf, acc[mt][nt], 0, 0, 0);
        }
        __syncthreads();
    }

    #pragma unroll
    for (int nt = 0; nt < 4; ++nt) {
        const int col = bn + nt * 16 + lr;
        const float bias = b2[col];
        #pragma unroll
        for (int mt = 0; mt < 2; ++mt)
            #pragma unroll
            for (int i = 0; i < 4; ++i) {
                const int row = bm + w * 32 + mt * 16 + lg * 4 + i;
                out[(size_t)row * HDIM + col] = acc[mt][nt][i] + bias;
            }
    }
}

// ---------------------------------------------------------------------------
extern "C" void kernel_launch(void* const* d_in, const int* in_sizes, int n_in,
                              void* d_out, int out_size, void* d_ws, size_t ws_size,
                              hipStream_t stream) {
    const float* x        = (const float*)d_in[0];
    const float* pos      = (const float*)d_in[1];
    const float* x_skip   = (const float*)d_in[2];
    const float* pos_skip = (const float*)d_in[3];
    const float* W1       = (const float*)d_in[4];
    const float* b1       = (const float*)d_in[5];
    const float* W2       = (const float*)d_in[6];
    const float* b2       = (const float*)d_in[7];

    // d_ws layout (needs 12.5 MB; A used 12.58 MB in prior rounds):
    u16*    Hbuf = (u16*)d_ws;                               // [16384][256] bf16 = 8 MB
    float*  Z    = (float*)((char*)d_ws + (8u << 20));       // [4096][256] f32 = 4 MB
    float4* nbrw = (float4*)((char*)d_ws + (12u << 20));     // 256 KB
    uint4*  nbri = (uint4*)((char*)d_ws + (12u << 20) + (256u << 10)); // 256 KB

    // d_out scratch (dead before gemm2 writes):
    uint2*  candT = (uint2*)d_out;                           // [16][3][16384] = 6.29 MB
    float4* pos4  = (float4*)((char*)d_out + (8u << 20));    // 64 KB (+128B slack read)
    float*  out   = (float*)d_out;

    pack_pos4 <<<16, 256, 0, stream>>>(pos, pos4);
    knn_scan  <<<dim3(64, NSHARD), 256, 0, stream>>>(pos4, pos_skip, candT);
    knn_merge <<<64, 256, 0, stream>>>(candT, nbrw, nbri);
    gemm_Z    <<<dim3(32, 4), 256, 0, stream>>>(x, W1, Z);
    gemm_SH   <<<dim3(128, 4), 256, 0, stream>>>(x_skip, W1, b1, Z, nbrw, nbri, Hbuf);
    gemm2_mfma<<<dim3(128, 4), 256, 0, stream>>>(Hbuf, W2, b2, out);
}

// Round 8
// 88.760 us; speedup vs baseline: 4.7678x; 1.0701x over previous
//
#include <hip/hip_runtime.h>
#include <hip/hip_bf16.h>

#define N_PTS 4096
#define M_PTS 16384
#define CIN   256
#define CSK   128
#define KDIM  384   // CIN + CSK
#define HDIM  256
#define NSHARD 32
#define SHPTS (N_PTS / NSHARD)   // 128

typedef unsigned int  u32;
typedef unsigned short u16;
typedef __attribute__((ext_vector_type(8))) short bf16x8;
typedef __attribute__((ext_vector_type(4))) float f32x4;

__device__ __forceinline__ u16 f2bf(float f) {
    union { float f; u32 i; } w; w.f = f;
    u32 x = w.i;
    u32 r = x + 0x7fffu + ((x >> 16) & 1u);   // RTNE
    return (u16)(r >> 16);
}

// strict "better" with lower-index tie-break (stable-sort semantics)
__device__ __forceinline__ bool ltk(float s, int p, float t, int i) {
    return (s < t) || (s == t && p < i);
}
__device__ __forceinline__ void ins3(float s, int p,
                                     float& t0, float& t1, float& t2,
                                     int& i0, int& i1, int& i2) {
    if (ltk(s, p, t2, i2)) {
        if (ltk(s, p, t1, i1)) {
            t2 = t1; i2 = i1;
            if (ltk(s, p, t0, i0)) { t1 = t0; i1 = i0; t0 = s; i0 = p; }
            else                   { t1 = s;  i1 = p; }
        } else { t2 = s; i2 = p; }
    }
}

// branchless sorted top-3 insert, strict < (ascending-index stream => stable)
#define INS3BL(s, p, t0, t1, t2, i0, i1, i2)                              \
    {                                                                     \
        float _o0 = t0, _o1 = t1, _o2 = t2;                               \
        int _a0 = i0, _a1 = i1, _a2 = i2;                                 \
        bool _c0 = (s) < _o0, _c1 = (s) < _o1, _c2 = (s) < _o2;           \
        t0 = _c0 ? (s) : _o0;              i0 = _c0 ? (p) : _a0;          \
        t1 = _c0 ? _o0 : (_c1 ? (s) : _o1); i1 = _c0 ? _a0 : (_c1 ? (p) : _a1); \
        t2 = _c1 ? _o1 : (_c2 ? (s) : _o2); i2 = _c1 ? _a1 : (_c2 ? (p) : _a2); \
    }

// ---------------------------------------------------------------------------
// Kernel 0: W1 [384][256] f32 -> W1T [256][384] bf16 (transposed, RTNE)
// ---------------------------------------------------------------------------
__global__ __launch_bounds__(384) void prep_w1t(
    const float* __restrict__ W1, u16* __restrict__ W1T)
{
    const int n = blockIdx.x;       // 256 blocks
    const int k = threadIdx.x;      // 384 threads
    W1T[(size_t)n * KDIM + k] = f2bf(W1[(size_t)k * HDIM + n]);
}

// ---------------------------------------------------------------------------
// Kernel 1: sharded 3-NN scan. One query per THREAD; shard points staged in
// LDS (uniform ds_read broadcast); 4 interleaved top-3 chains.
// Bit-exact fp32 d^2 = (|q|^2 - 2*fma(qz,pz,fma(qy,py,qx*px))) + |p|^2.
// Output TRANSPOSED: candT[(sh*3+k)*M + m]  (coalesced write AND read).
// ---------------------------------------------------------------------------
__global__ __launch_bounds__(256, 8) void knn_scan(
    const float* __restrict__ pos,
    const float* __restrict__ pos_skip,
    uint2* __restrict__ candT)
{
    __shared__ float4 spts[SHPTS];     // 128 x 16B = 2 KB
    const int tid = threadIdx.x;
    const int m  = blockIdx.x * 256 + tid;
    const int sh = blockIdx.y;
    const int pbase = sh * SHPTS;

    if (tid < SHPTS) {
        const int i = pbase + tid;
        float px = pos[3 * i], py = pos[3 * i + 1], pz = pos[3 * i + 2];
        float pn = __fadd_rn(__fadd_rn(__fmul_rn(px, px), __fmul_rn(py, py)),
                             __fmul_rn(pz, pz));
        spts[tid] = make_float4(px, py, pz, pn);
    }

    const float qx = pos_skip[3 * m];
    const float qy = pos_skip[3 * m + 1];
    const float qz = pos_skip[3 * m + 2];
    const float qn = __fadd_rn(__fadd_rn(__fmul_rn(qx, qx), __fmul_rn(qy, qy)),
                               __fmul_rn(qz, qz));
    __syncthreads();

    float e0[4], e1[4], e2[4];
    int   a0[4], a1[4], a2[4];
    #pragma unroll
    for (int c = 0; c < 4; ++c) {
        e0[c] = 3.4e38f; e1[c] = 3.4e38f; e2[c] = 3.4e38f;
        a0[c] = 0x7fffffff; a1[c] = 0x7fffffff; a2[c] = 0x7fffffff;
    }

    #pragma unroll 8
    for (int j = 0; j < SHPTS; ++j) {
        float4 v = spts[j];            // uniform broadcast read
        // b = q.p as fma chain (k ascending), bit-exact vs reference
        float b = __fmaf_rn(qz, v.z, __fmaf_rn(qy, v.y, __fmul_rn(qx, v.x)));
        // s = (qn - 2b) + pn ; qn - 2b == fma(-2, b, qn) exactly (2b exact)
        float s = __fadd_rn(__fmaf_rn(-2.0f, b, qn), v.w);
        const int p = pbase + j;
        const int c = j & 3;
        INS3BL(s, p, e0[c], e1[c], e2[c], a0[c], a1[c], a2[c]);
    }
    // merge chains 1..3 into chain 0 (value, then lower-index tie-break)
    #pragma unroll
    for (int c = 1; c < 4; ++c) {
        ins3(e0[c], a0[c], e0[0], e1[0], e2[0], a0[0], a1[0], a2[0]);
        ins3(e1[c], a1[c], e0[0], e1[0], e2[0], a0[0], a1[0], a2[0]);
        ins3(e2[c], a2[c], e0[0], e1[0], e2[0], a0[0], a1[0], a2[0]);
    }

    candT[(size_t)(sh * 3 + 0) * M_PTS + m] = make_uint2(__float_as_uint(e0[0]), (u32)a0[0]);
    candT[(size_t)(sh * 3 + 1) * M_PTS + m] = make_uint2(__float_as_uint(e1[0]), (u32)a1[0]);
    candT[(size_t)(sh * 3 + 2) * M_PTS + m] = make_uint2(__float_as_uint(e2[0]), (u32)a2[0]);
}

// ---------------------------------------------------------------------------
// Kernel 2: per-lane merge of 32 shard top-3 lists -> normalized weights+idx.
// Shard-ascending + k-ascending insert order with strict < == stable order.
// ---------------------------------------------------------------------------
__global__ __launch_bounds__(256) void knn_merge(
    const uint2* __restrict__ candT,   // [32][3][M]
    float4* __restrict__ nbrw,         // [M] (w0,w1,w2,-) normalized
    uint4* __restrict__ nbri)          // [M] (i0,i1,i2,-)
{
    const int m = blockIdx.x * 256 + threadIdx.x;

    float t0 = 3.4e38f, t1 = 3.4e38f, t2 = 3.4e38f;
    int   i0 = 0x7fffffff, i1 = 0x7fffffff, i2 = 0x7fffffff;

    #pragma unroll
    for (int sh = 0; sh < NSHARD; ++sh) {
        #pragma unroll
        for (int k = 0; k < 3; ++k) {
            uint2 v = candT[(size_t)(sh * 3 + k) * M_PTS + m];
            float s = __uint_as_float(v.x);
            const int p = (int)v.y;
            INS3BL(s, p, t0, t1, t2, i0, i1, i2);
        }
    }

    float w0 = __fdiv_rn(1.0f, fmaxf(t0, 1e-16f));
    float w1 = __fdiv_rn(1.0f, fmaxf(t1, 1e-16f));
    float w2 = __fdiv_rn(1.0f, fmaxf(t2, 1e-16f));
    float inv = __fdiv_rn(1.0f, __fadd_rn(__fadd_rn(w0, w1), w2));
    nbrw[m] = make_float4(w0 * inv, w1 * inv, w2 * inv, 0.f);
    nbri[m] = make_uint4((u32)i0, (u32)i1, (u32)i2, 0u);
}

// ---------------------------------------------------------------------------
// Kernel 3 (MFMA): Z = bf16(x) @ bf16(W1[:256,:])   [4096, 256], no bias.
// B staged from pre-converted W1T (vector 16B load + ds_write_b128).
// ---------------------------------------------------------------------------
__global__ __launch_bounds__(256) void gemm_Z(
    const float* __restrict__ x, const u16* __restrict__ W1T,
    float* __restrict__ Z)
{
    __shared__ alignas(16) u16 Bs[64][40];
    const int tid = threadIdx.x;
    const int w = tid >> 6, l = tid & 63;
    const int bm = blockIdx.x * 128;
    const int bn = blockIdx.y * 64;
    const int lr = l & 15, lg = l >> 4;

    f32x4 acc[2][4];
    #pragma unroll
    for (int mt = 0; mt < 2; ++mt)
        #pragma unroll
        for (int nt = 0; nt < 4; ++nt)
            acc[mt][nt] = (f32x4){0.f, 0.f, 0.f, 0.f};

    const int sc = tid >> 2;
    const int sk = (tid & 3) * 8;

    for (int k0 = 0; k0 < CIN; k0 += 32) {
        *reinterpret_cast<bf16x8*>(&Bs[sc][sk]) =
            *reinterpret_cast<const bf16x8*>(&W1T[(size_t)(bn + sc) * KDIM + k0 + sk]);
        __syncthreads();

        bf16x8 af[2];
        #pragma unroll
        for (int mt = 0; mt < 2; ++mt) {
            const float* xp = x + (size_t)(bm + w * 32 + mt * 16 + lr) * CIN + k0 + lg * 8;
            float4 h0 = *reinterpret_cast<const float4*>(xp);
            float4 h1 = *reinterpret_cast<const float4*>(xp + 4);
            af[mt][0] = (short)f2bf(h0.x); af[mt][1] = (short)f2bf(h0.y);
            af[mt][2] = (short)f2bf(h0.z); af[mt][3] = (short)f2bf(h0.w);
            af[mt][4] = (short)f2bf(h1.x); af[mt][5] = (short)f2bf(h1.y);
            af[mt][6] = (short)f2bf(h1.z); af[mt][7] = (short)f2bf(h1.w);
        }
        #pragma unroll
        for (int nt = 0; nt < 4; ++nt) {
            bf16x8 bf = *reinterpret_cast<const bf16x8*>(&Bs[nt * 16 + lr][lg * 8]);
            #pragma unroll
            for (int mt = 0; mt < 2; ++mt)
                acc[mt][nt] = __builtin_amdgcn_mfma_f32_16x16x32_bf16(
                    af[mt], bf, acc[mt][nt], 0, 0, 0);
        }
        __syncthreads();
    }

    #pragma unroll
    for (int nt = 0; nt < 4; ++nt) {
        const int col = bn + nt * 16 + lr;
        #pragma unroll
        for (int mt = 0; mt < 2; ++mt)
            #pragma unroll
            for (int i = 0; i < 4; ++i) {
                const int row = bm + w * 32 + mt * 16 + lg * 4 + i;
                Z[(size_t)row * HDIM + col] = acc[mt][nt][i];
            }
    }
}

// ---------------------------------------------------------------------------
// Kernel 4 (MFMA): S = bf16(x_skip) @ bf16(W1[256:,:]); epilogue fuses the
// knn interpolation: H = relu(S + sum_k w_k Z[i_k] + b1), H stored bf16.
// ---------------------------------------------------------------------------
__global__ __launch_bounds__(256) void gemm_SH(
    const float* __restrict__ x_skip, const u16* __restrict__ W1T,
    const float* __restrict__ b1, const float* __restrict__ Z,
    const float4* __restrict__ nbrw, const uint4* __restrict__ nbri,
    u16* __restrict__ H)
{
    __shared__ alignas(16) u16 Bs[64][40];
    const int tid = threadIdx.x;
    const int w = tid >> 6, l = tid & 63;
    const int bm = blockIdx.x * 128;
    const int bn = blockIdx.y * 64;
    const int lr = l & 15, lg = l >> 4;

    f32x4 acc[2][4];
    #pragma unroll
    for (int mt = 0; mt < 2; ++mt)
        #pragma unroll
        for (int nt = 0; nt < 4; ++nt)
            acc[mt][nt] = (f32x4){0.f, 0.f, 0.f, 0.f};

    const int sc = tid >> 2;
    const int sk = (tid & 3) * 8;

    for (int k0 = 0; k0 < CSK; k0 += 32) {
        *reinterpret_cast<bf16x8*>(&Bs[sc][sk]) =
            *reinterpret_cast<const bf16x8*>(&W1T[(size_t)(bn + sc) * KDIM + CIN + k0 + sk]);
        __syncthreads();

        bf16x8 af[2];
        #pragma unroll
        for (int mt = 0; mt < 2; ++mt) {
            const float* xp = x_skip + (size_t)(bm + w * 32 + mt * 16 + lr) * CSK + k0 + lg * 8;
            float4 h0 = *reinterpret_cast<const float4*>(xp);
            float4 h1 = *reinterpret_cast<const float4*>(xp + 4);
            af[mt][0] = (short)f2bf(h0.x); af[mt][1] = (short)f2bf(h0.y);
            af[mt][2] = (short)f2bf(h0.z); af[mt][3] = (short)f2bf(h0.w);
            af[mt][4] = (short)f2bf(h1.x); af[mt][5] = (short)f2bf(h1.y);
            af[mt][6] = (short)f2bf(h1.z); af[mt][7] = (short)f2bf(h1.w);
        }
        #pragma unroll
        for (int nt = 0; nt < 4; ++nt) {
            bf16x8 bf = *reinterpret_cast<const bf16x8*>(&Bs[nt * 16 + lr][lg * 8]);
            #pragma unroll
            for (int mt = 0; mt < 2; ++mt)
                acc[mt][nt] = __builtin_amdgcn_mfma_f32_16x16x32_bf16(
                    af[mt], bf, acc[mt][nt], 0, 0, 0);
        }
        __syncthreads();
    }

    // epilogue: blend interpolated Z rows + bias + relu -> H (bf16)
    #pragma unroll
    for (int mt = 0; mt < 2; ++mt) {
        #pragma unroll
        for (int i = 0; i < 4; ++i) {
            const int row = bm + w * 32 + mt * 16 + lg * 4 + i;
            const float4 wv = nbrw[row];
            const uint4  iv = nbri[row];
            const float* z0 = Z + (size_t)iv.x * HDIM;
            const float* z1 = Z + (size_t)iv.y * HDIM;
            const float* z2 = Z + (size_t)iv.z * HDIM;
            #pragma unroll
            for (int nt = 0; nt < 4; ++nt) {
                const int col = bn + nt * 16 + lr;
                float zb = wv.x * z0[col] + wv.y * z1[col] + wv.z * z2[col];
                float v = acc[mt][nt][i] + zb + b1[col];
                H[(size_t)row * HDIM + col] = f2bf(v > 0.f ? v : 0.f);
            }
        }
    }
}

// ---------------------------------------------------------------------------
// Kernel 5 (MFMA): out = H @ W2 + b2.  H bf16 [16384,256], out f32.
// ---------------------------------------------------------------------------
__global__ __launch_bounds__(256) void gemm2_mfma(
    const u16* __restrict__ H, const float* __restrict__ W2,
    const float* __restrict__ b2, float* __restrict__ out)
{
    __shared__ alignas(16) u16 Bs[64][40];
    const int tid = threadIdx.x;
    const int w = tid >> 6, l = tid & 63;
    const int bm = blockIdx.x * 128;
    const int bn = blockIdx.y * 64;
    const int lr = l & 15, lg = l >> 4;

    f32x4 acc[2][4];
    #pragma unroll
    for (int mt = 0; mt < 2; ++mt)
        #pragma unroll
        for (int nt = 0; nt < 4; ++nt)
            acc[mt][nt] = (f32x4){0.f, 0.f, 0.f, 0.f};

    const int sc = tid >> 2;
    const int sk = (tid & 3) * 8;

    for (int k0 = 0; k0 < HDIM; k0 += 32) {
        #pragma unroll
        for (int j = 0; j < 8; ++j)
            Bs[sc][sk + j] = f2bf(W2[(size_t)(k0 + sk + j) * HDIM + bn + sc]);
        __syncthreads();

        bf16x8 af[2];
        #pragma unroll
        for (int mt = 0; mt < 2; ++mt) {
            const int row = bm + w * 32 + mt * 16 + lr;
            af[mt] = *reinterpret_cast<const bf16x8*>(H + (size_t)row * HDIM + k0 + lg * 8);
        }
        #pragma unroll
        for (int nt = 0; nt < 4; ++nt) {
            bf16x8 bf = *reinterpret_cast<const bf16x8*>(&Bs[nt * 16 + lr][lg * 8]);
            #pragma unroll
            for (int mt = 0; mt < 2; ++mt)
                acc[mt][nt] = __builtin_amdgcn_mfma_f32_16x16x32_bf16(
                    af[mt], bf, acc[mt][nt], 0, 0, 0);
        }
        __syncthreads();
    }

    #pragma unroll
    for (int nt = 0; nt < 4; ++nt) {
        const int col = bn + nt * 16 + lr;
        const float bias = b2[col];
        #pragma unroll
        for (int mt = 0; mt < 2; ++mt)
            #pragma unroll
            for (int i = 0; i < 4; ++i) {
                const int row = bm + w * 32 + mt * 16 + lg * 4 + i;
                out[(size_t)row * HDIM + col] = acc[mt][nt][i] + bias;
            }
    }
}

// ---------------------------------------------------------------------------
extern "C" void kernel_launch(void* const* d_in, const int* in_sizes, int n_in,
                              void* d_out, int out_size, void* d_ws, size_t ws_size,
                              hipStream_t stream) {
    const float* x        = (const float*)d_in[0];
    const float* pos      = (const float*)d_in[1];
    const float* x_skip   = (const float*)d_in[2];
    const float* pos_skip = (const float*)d_in[3];
    const float* W1       = (const float*)d_in[4];
    const float* b1       = (const float*)d_in[5];
    const float* W2       = (const float*)d_in[6];
    const float* b2       = (const float*)d_in[7];

    // d_ws (within proven 12.5 MiB): Hbuf 8M | Z 4M | nbrw 256K | nbri 256K
    u16*    Hbuf = (u16*)d_ws;                               // [16384][256] bf16
    float*  Z    = (float*)((char*)d_ws + (8u << 20));       // [4096][256] f32
    float4* nbrw = (float4*)((char*)d_ws + (12u << 20));
    uint4*  nbri = (uint4*)((char*)d_ws + (12u << 20) + (256u << 10));

    // d_out scratch (all dead before gemm2 writes out):
    uint2* candT = (uint2*)d_out;                            // [32][3][16384] = 12.58 MB
    u16*   W1T   = (u16*)((char*)d_out + (14u << 20));       // [256][384] bf16 = 192 KB
    float* out   = (float*)d_out;

    prep_w1t  <<<256, 384, 0, stream>>>(W1, W1T);
    knn_scan  <<<dim3(64, NSHARD), 256, 0, stream>>>(pos, pos_skip, candT);
    knn_merge <<<64, 256, 0, stream>>>(candT, nbrw, nbri);
    gemm_Z    <<<dim3(32, 4), 256, 0, stream>>>(x, W1T, Z);
    gemm_SH   <<<dim3(128, 4), 256, 0, stream>>>(x_skip, W1T, b1, Z, nbrw, nbri, Hbuf);
    gemm2_mfma<<<dim3(128, 4), 256, 0, stream>>>(Hbuf, W2, b2, out);
}